// Round 7
// baseline (250.774 us; speedup 1.0000x reference)
//
#include <hip/hip_runtime.h>

// KernelizedHeadAttention, B=4 S=1024 D=2048 H=16 DH=128 DHID=128 DKER=64
// out[s] = [ sum_t (m? score+eps : exp(saw)) * v[t] ] / (rowsum_s + eps + exp(lse_s))
// R7: the R4-R6 attn was LDS-pipe-bound (6.1k cy/block-phase, arithmetic matches 163us).
// Fix: SWAPPED QK^T (mfma(K,Q)) so each lane owns one s-row x 16 t-cols. Then:
//  - saw/mask load per-lane float4/uchar4 straight from global (no ebuf, no LDS merge)
//  - merge+exp+rowsum in registers; P redistributed to PV B-frags via tiny wave-private
//    p_lds (4 ds_write_b64 + 2 ds_read_b128 per wave-phase)
//  - PV = mfma(V,P) -> per-lane float4 output stores
//  - mask pre-normalized to uchar once (prep_mask) to cut register pressure
// LDS traffic per block-phase drops ~6x; V tile (b128 floor) is the only big consumer.

typedef __bf16 bf16_t;
typedef __attribute__((ext_vector_type(8))) __bf16 bf16x8;
typedef __attribute__((ext_vector_type(4))) float f32x4;

#define MFMA(a, b, c) __builtin_amdgcn_mfma_f32_16x16x32_bf16((a), (b), (c), 0, 0, 0)

typedef __attribute__((address_space(3))) void as3_void;
typedef __attribute__((address_space(1))) const void as1_void;
static __device__ __forceinline__ void gload16(const void* g, void* l) {
    __builtin_amdgcn_global_load_lds((as1_void*)g, (as3_void*)l, 16, 0, 0);
}

static __device__ __forceinline__ float gelu_exact(float x) {
    return 0.5f * x * (1.0f + erff(x * 0.70710678118654752f));
}

static __device__ __forceinline__ unsigned pack_bf16(float a, float b) {
    bf16_t x = (bf16_t)a, y = (bf16_t)b;
    unsigned short ux = __builtin_bit_cast(unsigned short, x);
    unsigned short uy = __builtin_bit_cast(unsigned short, y);
    return (unsigned)ux | ((unsigned)uy << 16);
}

// ---------------- weights: convert f32 -> bf16, transposed for B-fragments ----------------
__global__ __launch_bounds__(256) void conv_weights_kernel(
    const float* __restrict__ wq1, const float* __restrict__ wk1,
    const float* __restrict__ wq2, const float* __restrict__ wk2,
    const float* __restrict__ iK,
    bf16_t* __restrict__ wq1t, bf16_t* __restrict__ wk1t,
    bf16_t* __restrict__ wq2t, bf16_t* __restrict__ wk2t,
    bf16_t* __restrict__ iKt)
{
    const int idx = blockIdx.x * 256 + threadIdx.x;
    if (idx < 16 * 128 * 128) {           // [h][e][d] <- [h][d][e]
        int h = idx >> 14, e = (idx >> 7) & 127, d = idx & 127;
        wq1t[idx] = (bf16_t)wq1[(h << 14) + (d << 7) + e];
        wk1t[idx] = (bf16_t)wk1[(h << 14) + (d << 7) + e];
    }
    if (idx < 16 * 64 * 128) {            // [h][f][e] <- [h][e][f]
        int h = idx >> 13, f = (idx >> 7) & 63, e = idx & 127;
        wq2t[idx] = (bf16_t)wq2[(h << 13) + (e << 6) + f];
        wk2t[idx] = (bf16_t)wk2[(h << 13) + (e << 6) + f];
    }
    if (idx < 16 * 64 * 64) {             // [h][g][f] <- [h][f][g]
        int h = idx >> 12, g = (idx >> 6) & 63, f = idx & 63;
        iKt[idx] = (bf16_t)iK[(h << 12) + (f << 6) + g];
    }
}

// ---------------- mask: normalize to uchar [B,S,S] (handles int32 or byte input) --------
__global__ __launch_bounds__(256) void prep_mask_kernel(
    const unsigned char* __restrict__ mask8, unsigned char* __restrict__ mout)
{
    __shared__ int mflag;
    const int tid = threadIdx.x;
    if (tid == 0) {     // int32 storage => bytes 4i+1 all zero over first 64 elems
        unsigned a = 0;
        for (int i = 0; i < 64; ++i) a |= mask8[4 * i + 1];
        mflag = (a == 0) ? 1 : 0;
    }
    __syncthreads();
    const size_t base = ((size_t)blockIdx.x * 256 + tid) * 16;   // 16 bytes out/thread
    if (mflag) {
        const int* mi = (const int*)mask8;
        uint4 r;
        unsigned bs[4];
#pragma unroll
        for (int j = 0; j < 4; ++j) {
            int4 v = *reinterpret_cast<const int4*>(&mi[base + j * 4]);
            bs[j] = (v.x ? 1u : 0u) | ((v.y ? 1u : 0u) << 8) |
                    ((v.z ? 1u : 0u) << 16) | ((v.w ? 1u : 0u) << 24);
        }
        r.x = bs[0]; r.y = bs[1]; r.z = bs[2]; r.w = bs[3];
        *reinterpret_cast<uint4*>(&mout[base]) = r;
    } else {
        uint4 v = *reinterpret_cast<const uint4*>(&mask8[base]);
        // normalize nonzero bytes to 1
        uint4 r;
        unsigned* pv = (unsigned*)&v;
        unsigned* pr = (unsigned*)&r;
#pragma unroll
        for (int j = 0; j < 4; ++j) {
            unsigned x = pv[j], o = 0;
#pragma unroll
            for (int k = 0; k < 4; ++k)
                o |= (((x >> (8 * k)) & 255u) ? 1u : 0u) << (8 * k);
            pr[j] = o;
        }
        *reinterpret_cast<uint4*>(&mout[base]) = r;
    }
}

// ---------------- V: [B,S,H,128] f32 -> vT tiled [B,H,tt(16),128,64] bf16 ---------------
__global__ __launch_bounds__(256) void conv_v_kernel(
    const float* __restrict__ v, bf16_t* __restrict__ vT)
{
    __shared__ bf16_t tr[128][72];
    const int bh = blockIdx.x, b = bh >> 4, h = bh & 15;
    const int tt = blockIdx.y;
    const int t0 = tt * 64;
    const int tid = threadIdx.x;
#pragma unroll
    for (int i = 0; i < 8; ++i) {
        int f4 = tid + 256 * i;                 // 2048 float4 = 64 t x 128 d
        int t = f4 >> 5, c4 = f4 & 31;
        const float4 vv = *reinterpret_cast<const float4*>(
            &v[((size_t)b * 1024 + t0 + t) * 2048 + h * 128 + c4 * 4]);
        tr[c4 * 4 + 0][t] = (bf16_t)vv.x;
        tr[c4 * 4 + 1][t] = (bf16_t)vv.y;
        tr[c4 * 4 + 2][t] = (bf16_t)vv.z;
        tr[c4 * 4 + 3][t] = (bf16_t)vv.w;
    }
    __syncthreads();
#pragma unroll
    for (int i = 0; i < 32; ++i) {
        int e = tid + 256 * i;                  // 8192 bf16
        int d = e >> 6, tl = e & 63;
        vT[(((size_t)bh * 16 + tt) * 128 + d) * 64 + tl] = tr[d][tl];
    }
}

// ---------------- feature maps: qf = |gelu(gelu(q W1) W2)|, kf path w/ interaction ------
__global__ __launch_bounds__(256) void feat_kernel(
    const float* __restrict__ q, const float* __restrict__ k,
    const bf16_t* __restrict__ wq1t, const bf16_t* __restrict__ wq2t,
    const bf16_t* __restrict__ wk1t, const bf16_t* __restrict__ wk2t,
    const bf16_t* __restrict__ iKt,
    const float* __restrict__ sD, const float* __restrict__ sD2,
    bf16_t* __restrict__ qf, bf16_t* __restrict__ kf)
{
    __shared__ bf16_t xa[64][136];
    __shared__ bf16_t h1[64][136];
    __shared__ bf16_t k2[64][72];

    const int tid = threadIdx.x;
    const int lane = tid & 63, w = tid >> 6;
    const int lr = lane & 15, lg = lane >> 4;
    const int row0 = blockIdx.x * 64;
    const int h = blockIdx.y;
    const int path = blockIdx.z;               // 0 = q, 1 = k

    const float* X = path ? k : q;
    const bf16_t* w1t = path ? wk1t : wq1t;
    const bf16_t* w2t = path ? wk2t : wq2t;
    bf16_t* outp = path ? kf : qf;

#pragma unroll
    for (int i = 0; i < 8; ++i) {
        int f4 = tid + 256 * i;
        int r = f4 >> 5, c4 = f4 & 31;
        const float4 vv = *reinterpret_cast<const float4*>(
            &X[(size_t)(row0 + r) * 2048 + h * 128 + c4 * 4]);
        xa[r][c4 * 4 + 0] = (bf16_t)vv.x;
        xa[r][c4 * 4 + 1] = (bf16_t)vv.y;
        xa[r][c4 * 4 + 2] = (bf16_t)vv.z;
        xa[r][c4 * 4 + 3] = (bf16_t)vv.w;
    }
    __syncthreads();

    bf16x8 a1[4];
#pragma unroll
    for (int kk = 0; kk < 4; ++kk)
        a1[kk] = *reinterpret_cast<const bf16x8*>(&xa[w * 16 + lr][kk * 32 + lg * 8]);
#pragma unroll
    for (int nt = 0; nt < 8; ++nt) {
        f32x4 acc = {0.f, 0.f, 0.f, 0.f};
#pragma unroll
        for (int kk = 0; kk < 4; ++kk) {
            bf16x8 bfr = *reinterpret_cast<const bf16x8*>(
                &w1t[(size_t)h * 16384 + (nt * 16 + lr) * 128 + kk * 32 + lg * 8]);
            acc = MFMA(a1[kk], bfr, acc);
        }
#pragma unroll
        for (int r = 0; r < 4; ++r)
            h1[w * 16 + lg * 4 + r][nt * 16 + lr] = (bf16_t)gelu_exact(acc[r]);
    }
    __syncthreads();

    bf16x8 a2[4];
#pragma unroll
    for (int kk = 0; kk < 4; ++kk)
        a2[kk] = *reinterpret_cast<const bf16x8*>(&h1[w * 16 + lr][kk * 32 + lg * 8]);

    if (path == 0) {
#pragma unroll
        for (int nt = 0; nt < 4; ++nt) {
            f32x4 acc = {0.f, 0.f, 0.f, 0.f};
#pragma unroll
            for (int kk = 0; kk < 4; ++kk) {
                bf16x8 bfr = *reinterpret_cast<const bf16x8*>(
                    &w2t[(size_t)h * 8192 + (nt * 16 + lr) * 128 + kk * 32 + lg * 8]);
                acc = MFMA(a2[kk], bfr, acc);
            }
#pragma unroll
            for (int r = 0; r < 4; ++r) {
                int n = row0 + w * 16 + lg * 4 + r;
                int bb = n >> 10, s = n & 1023;
                outp[(((size_t)bb * 16 + h) * 1024 + s) * 64 + nt * 16 + lr] =
                    (bf16_t)fabsf(gelu_exact(acc[r]));
            }
        }
    } else {
#pragma unroll
        for (int nt = 0; nt < 4; ++nt) {
            f32x4 acc = {0.f, 0.f, 0.f, 0.f};
#pragma unroll
            for (int kk = 0; kk < 4; ++kk) {
                bf16x8 bfr = *reinterpret_cast<const bf16x8*>(
                    &w2t[(size_t)h * 8192 + (nt * 16 + lr) * 128 + kk * 32 + lg * 8]);
                acc = MFMA(a2[kk], bfr, acc);
            }
#pragma unroll
            for (int r = 0; r < 4; ++r) {
                int f = nt * 16 + lr;
                k2[w * 16 + lg * 4 + r][f] =
                    (bf16_t)(fabsf(sD[h * 64 + f]) * gelu_exact(acc[r]));
            }
        }
        __syncthreads();
        bf16x8 a3[2];
#pragma unroll
        for (int kk = 0; kk < 2; ++kk)
            a3[kk] = *reinterpret_cast<const bf16x8*>(&k2[w * 16 + lr][kk * 32 + lg * 8]);
#pragma unroll
        for (int nt = 0; nt < 4; ++nt) {
            f32x4 acc = {0.f, 0.f, 0.f, 0.f};
#pragma unroll
            for (int kk = 0; kk < 2; ++kk) {
                bf16x8 bfr = *reinterpret_cast<const bf16x8*>(
                    &iKt[(size_t)h * 4096 + (nt * 16 + lr) * 64 + kk * 32 + lg * 8]);
                acc = MFMA(a3[kk], bfr, acc);
            }
#pragma unroll
            for (int r = 0; r < 4; ++r) {
                int row = w * 16 + lg * 4 + r;
                int g = nt * 16 + lr;
                float base = (float)k2[row][g];
                float kv = fabsf(base + acc[r] * sD2[h * 64 + g]);
                int n = row0 + row;
                int bb = n >> 10, s = n & 1023;
                outp[(((size_t)bb * 16 + h) * 1024 + s) * 64 + g] = (bf16_t)kv;
            }
        }
    }
}

// ---------------- fused attention: swapped-QK^T, register merge, minimal LDS ------------
__global__ __launch_bounds__(256, 3) void attn_swapped_kernel(
    const bf16_t* __restrict__ qf, const bf16_t* __restrict__ kf,
    const bf16_t* __restrict__ vT,
    const unsigned char* __restrict__ mprep,
    const float* __restrict__ saw, const float* __restrict__ lse,
    float* __restrict__ out)
{
    __shared__ bf16_t vbuf[2][128 * 64];      // XOR-swizzled V tiles (16KB each)
    __shared__ unsigned p_lds[4][16][36];     // wave-private P staging (9.2KB)

    const int tid = threadIdx.x;
    const int lane = tid & 63, w = tid >> 6;
    const int lr = lane & 15, lg = lane >> 4;

    // XCD swizzle: all 16 s-blocks of a bh share one XCD's L2
    const int di = blockIdx.y * 16 + blockIdx.x;   // 0..1023
    const int xcd = di & 7, rr = di >> 3;
    const int bh = xcd + 8 * (rr >> 4);
    const int s0 = (rr & 15) * 64;
    const int b = bh >> 4, h = bh & 15;

    const int srow = s0 + w * 16 + lr;             // this lane's single s-row
    const size_t saw_row = ((size_t)bh << 20) + (size_t)srow * 1024;
    const size_t m_row   = ((size_t)b << 20) + (size_t)srow * 1024;

    // vT staging mapping (inverse-swizzled global source, linear LDS dest)
    const int vrow = tid >> 3;                     // 0..31 (+32 per j-round)
    const int vcol8 = (tid & 7) ^ (vrow & 7);
    const bf16_t* vt_bh = vT + (size_t)bh * 131072;

    // Q as B-fragments (n = s, k = f)
    bf16x8 aq0, aq1;
    {
        const size_t qb = ((size_t)bh * 1024 + srow) * 64;
        aq0 = *reinterpret_cast<const bf16x8*>(&qf[qb + lg * 8]);
        aq1 = *reinterpret_cast<const bf16x8*>(&qf[qb + 32 + lg * 8]);
    }

    const f32x4 fzero = {0.f, 0.f, 0.f, 0.f};
    f32x4 oacc[8];
#pragma unroll
    for (int i = 0; i < 8; ++i) oacc[i] = fzero;
    float rowsum = 0.f;
    const int xorv = (lr & 7) << 4;

#define STAGE_VT(BUF, TILE)                                                      \
    {                                                                            \
        const bf16_t* vg = vt_bh + (size_t)(TILE) * 8192 + vcol8 * 8;            \
        char* lb = (char*)&vbuf[BUF][0] + w * 1024;                              \
        _Pragma("unroll")                                                        \
        for (int j = 0; j < 4; ++j)                                              \
            gload16(vg + (size_t)(32 * j + vrow) * 64, lb + j * 4096);           \
    }

// per-lane saw (4x float4) + mask (4x uchar4) for one t-tile, in the QK^T-D layout
#define LOAD_SAW(TILE, SS, MM)                                                   \
    {                                                                            \
        _Pragma("unroll")                                                        \
        for (int nt = 0; nt < 4; ++nt) {                                         \
            SS[nt] = *reinterpret_cast<const f32x4*>(                            \
                &saw[saw_row + (TILE) * 64 + nt * 16 + lg * 4]);                 \
            MM[nt] = *reinterpret_cast<const unsigned*>(                         \
                &mprep[m_row + (TILE) * 64 + nt * 16 + lg * 4]);                 \
        }                                                                        \
    }

// kf as A-fragments for one t-tile (m = t, k = f); single-buffered (XCD-L2-hot)
#define LOAD_KF(TILE, KR)                                                        \
    {                                                                            \
        _Pragma("unroll")                                                        \
        for (int nt = 0; nt < 4; ++nt) {                                         \
            const size_t kb = ((size_t)bh * 1024 + (TILE) * 64 + nt * 16 + lr) * 64; \
            KR[nt * 2]     = *reinterpret_cast<const bf16x8*>(&kf[kb + lg * 8]); \
            KR[nt * 2 + 1] = *reinterpret_cast<const bf16x8*>(&kf[kb + 32 + lg * 8]); \
        }                                                                        \
    }

// one t-tile phase: QK^T (swapped) -> register merge -> p_lds redistrib -> PV
#define PHASE(CUR, SS, MM)                                                       \
    {                                                                            \
        f32x4 c[4];                                                              \
        _Pragma("unroll")                                                        \
        for (int nt = 0; nt < 4; ++nt) {                                         \
            f32x4 acc = fzero;                                                   \
            acc = MFMA(kfR[nt * 2], aq0, acc);                                   \
            acc = MFMA(kfR[nt * 2 + 1], aq1, acc);                               \
            c[nt] = acc;                                                         \
        }                                                                        \
        unsigned pk[8];                                                          \
        _Pragma("unroll")                                                        \
        for (int nt = 0; nt < 4; ++nt) {                                         \
            float v0, v1, v2, v3;                                                \
            {                                                                    \
                unsigned m0 = (MM[nt]) & 255u;                                   \
                float sc = c[nt][0];                                             \
                v0 = m0 ? (sc + 1e-6f) : __expf(SS[nt][0]);                      \
                rowsum += m0 ? sc : 0.f;                                         \
            }                                                                    \
            {                                                                    \
                unsigned m1 = (MM[nt] >> 8) & 255u;                              \
                float sc = c[nt][1];                                             \
                v1 = m1 ? (sc + 1e-6f) : __expf(SS[nt][1]);                      \
                rowsum += m1 ? sc : 0.f;                                         \
            }                                                                    \
            {                                                                    \
                unsigned m2 = (MM[nt] >> 16) & 255u;                             \
                float sc = c[nt][2];                                             \
                v2 = m2 ? (sc + 1e-6f) : __expf(SS[nt][2]);                      \
                rowsum += m2 ? sc : 0.f;                                         \
            }                                                                    \
            {                                                                    \
                unsigned m3 = (MM[nt] >> 24) & 255u;                             \
                float sc = c[nt][3];                                             \
                v3 = m3 ? (sc + 1e-6f) : __expf(SS[nt][3]);                      \
                rowsum += m3 ? sc : 0.f;                                         \
            }                                                                    \
            pk[nt * 2]     = pack_bf16(v0, v1);                                  \
            pk[nt * 2 + 1] = pack_bf16(v2, v3);                                  \
        }                                                                        \
        /* redistribute P: write t-slices, read k-contiguous B-frags */          \
        _Pragma("unroll")                                                        \
        for (int nt = 0; nt < 4; ++nt) {                                         \
            uint2 wv; wv.x = pk[nt * 2]; wv.y = pk[nt * 2 + 1];                  \
            *reinterpret_cast<uint2*>(&p_lds[w][lr][nt * 8 + lg * 2]) = wv;      \
        }                                                                        \
        bf16x8 pb0 = *reinterpret_cast<const bf16x8*>(&p_lds[w][lr][lg * 4]);    \
        bf16x8 pb1 = *reinterpret_cast<const bf16x8*>(&p_lds[w][lr][16 + lg * 4]); \
        const char* vb = (const char*)&vbuf[CUR][0];                             \
        _Pragma("unroll")                                                        \
        for (int dt = 0; dt < 8; ++dt) {                                         \
            const int row = dt * 16 + lr;                                        \
            bf16x8 v0 = *reinterpret_cast<const bf16x8*>(                        \
                vb + row * 128 + ((lg * 16) ^ xorv));                            \
            bf16x8 v1 = *reinterpret_cast<const bf16x8*>(                        \
                vb + row * 128 + ((64 + lg * 16) ^ xorv));                       \
            oacc[dt] = MFMA(v0, pb0, oacc[dt]);                                  \
            oacc[dt] = MFMA(v1, pb1, oacc[dt]);                                  \
        }                                                                        \
    }

    f32x4 sawA[4], sawB[4];
    unsigned muA[4], muB[4];
    bf16x8 kfR[8];

    // ---- prologue
    LOAD_SAW(0, sawA, muA);
    STAGE_VT(0, 0);
    __syncthreads();

    for (int i = 0; i < 16; i += 2) {
        // phase A: tile i, vbuf[0]
        STAGE_VT(1, i + 1);
        LOAD_SAW(i + 1, sawB, muB);
        LOAD_KF(i, kfR);
        PHASE(0, sawA, muA);
        __syncthreads();
        // phase B: tile i+1, vbuf[1]
        STAGE_VT(0, (i + 2) & 15);
        LOAD_SAW((i + 2) & 15, sawA, muA);
        LOAD_KF(i + 1, kfR);
        PHASE(1, sawB, muB);
        __syncthreads();
    }

    // rowsum: sum the 4 lg-partials for this s-row
    rowsum += __shfl_xor(rowsum, 16);
    rowsum += __shfl_xor(rowsum, 32);
    const float invden =
        1.0f / (rowsum + 1e-6f + __expf(lse[(size_t)bh * 1024 + srow]));

    const size_t ob = ((size_t)b * 1024 + srow) * 2048 + h * 128 + lg * 4;
#pragma unroll
    for (int dt = 0; dt < 8; ++dt) {
        f32x4 o;
        o[0] = oacc[dt][0] * invden;
        o[1] = oacc[dt][1] * invden;
        o[2] = oacc[dt][2] * invden;
        o[3] = oacc[dt][3] * invden;
        *reinterpret_cast<f32x4*>(&out[ob + dt * 16]) = o;
    }
#undef STAGE_VT
#undef LOAD_SAW
#undef LOAD_KF
#undef PHASE
}

extern "C" void kernel_launch(void* const* d_in, const int* in_sizes, int n_in,
                              void* d_out, int out_size, void* d_ws, size_t ws_size,
                              hipStream_t stream)
{
    const float* q   = (const float*)d_in[0];
    const float* k   = (const float*)d_in[1];
    const float* v   = (const float*)d_in[2];
    const unsigned char* mask = (const unsigned char*)d_in[3];
    const float* lse = (const float*)d_in[4];
    const float* saw = (const float*)d_in[5];
    const float* wq1 = (const float*)d_in[6];
    const float* wk1 = (const float*)d_in[7];
    const float* wq2 = (const float*)d_in[8];
    const float* wk2 = (const float*)d_in[9];
    const float* iK  = (const float*)d_in[10];
    const float* sD  = (const float*)d_in[11];
    const float* sD2 = (const float*)d_in[12];
    float* out = (float*)d_out;

    bf16_t* wsb  = (bf16_t*)d_ws;
    bf16_t* wq1t = wsb;                    // 16*128*128 = 262144
    bf16_t* wk1t = wq1t + 262144;
    bf16_t* wq2t = wk1t + 262144;          // 16*64*128 = 131072
    bf16_t* wk2t = wq2t + 131072;
    bf16_t* iKt  = wk2t + 131072;          // 16*64*64  = 65536
    bf16_t* qf   = iKt  + 65536;           // 4*16*1024*64 = 4194304
    bf16_t* kf   = qf   + 4194304;
    bf16_t* vT   = kf   + 4194304;         // 4*16*128*1024 = 8388608 (tiled)
    unsigned char* mprep = (unsigned char*)(vT + 8388608);  // 4MB uchar [B,S,S]
    // total ws use: ~39.3 MB

    conv_weights_kernel<<<dim3(1024), dim3(256), 0, stream>>>(
        wq1, wk1, wq2, wk2, iK, wq1t, wk1t, wq2t, wk2t, iKt);
    prep_mask_kernel<<<dim3(1024), dim3(256), 0, stream>>>(mask, mprep);
    conv_v_kernel<<<dim3(64, 16), dim3(256), 0, stream>>>(v, vT);
    feat_kernel<<<dim3(64, 16, 2), dim3(256), 0, stream>>>(
        q, k, wq1t, wq2t, wk1t, wk2t, iKt, sD, sD2, qf, kf);
    attn_swapped_kernel<<<dim3(16, 64), dim3(256), 0, stream>>>(
        qf, kf, vT, mprep, saw, lse, out);
}

// Round 9
// 208.502 us; speedup vs baseline: 1.2027x; 1.2027x over previous
//
#include <hip/hip_runtime.h>

// KernelizedHeadAttention, B=4 S=1024 D=2048 H=16 DH=128 DHID=128 DKER=64
// out[s] = [ sum_t (m? score+eps : exp(saw)) * v[t] ] / (rowsum_s + eps + exp(lse_s))
// R9 = R8 (counted-vmcnt pipeline) with the REDIST divergence bug fixed:
// R8 wrapped __shfl in a wave-divergent ternary (sel = lg<2); bpermute from an
// EXEC-disabled source lane returns garbage. Now all 16 shuffles execute at full
// EXEC, selection is a pure v_cndmask on the shuffled values.

typedef __bf16 bf16_t;
typedef __attribute__((ext_vector_type(8))) __bf16 bf16x8;
typedef __attribute__((ext_vector_type(4))) float f32x4;

#define MFMA(a, b, c) __builtin_amdgcn_mfma_f32_16x16x32_bf16((a), (b), (c), 0, 0, 0)

typedef __attribute__((address_space(3))) void as3_void;
typedef __attribute__((address_space(1))) const void as1_void;
static __device__ __forceinline__ void gload16(const void* g, void* l) {
    __builtin_amdgcn_global_load_lds((as1_void*)g, (as3_void*)l, 16, 0, 0);
}

static __device__ __forceinline__ float gelu_exact(float x) {
    return 0.5f * x * (1.0f + erff(x * 0.70710678118654752f));
}

static __device__ __forceinline__ unsigned pack_bf16(float a, float b) {
    bf16_t x = (bf16_t)a, y = (bf16_t)b;
    unsigned short ux = __builtin_bit_cast(unsigned short, x);
    unsigned short uy = __builtin_bit_cast(unsigned short, y);
    return (unsigned)ux | ((unsigned)uy << 16);
}

// ---------------- weights: convert f32 -> bf16, transposed for B-fragments ----------------
__global__ __launch_bounds__(256) void conv_weights_kernel(
    const float* __restrict__ wq1, const float* __restrict__ wk1,
    const float* __restrict__ wq2, const float* __restrict__ wk2,
    const float* __restrict__ iK,
    bf16_t* __restrict__ wq1t, bf16_t* __restrict__ wk1t,
    bf16_t* __restrict__ wq2t, bf16_t* __restrict__ wk2t,
    bf16_t* __restrict__ iKt)
{
    const int idx = blockIdx.x * 256 + threadIdx.x;
    if (idx < 16 * 128 * 128) {           // [h][e][d] <- [h][d][e]
        int h = idx >> 14, e = (idx >> 7) & 127, d = idx & 127;
        wq1t[idx] = (bf16_t)wq1[(h << 14) + (d << 7) + e];
        wk1t[idx] = (bf16_t)wk1[(h << 14) + (d << 7) + e];
    }
    if (idx < 16 * 64 * 128) {            // [h][f][e] <- [h][e][f]
        int h = idx >> 13, f = (idx >> 7) & 63, e = idx & 127;
        wq2t[idx] = (bf16_t)wq2[(h << 13) + (e << 6) + f];
        wk2t[idx] = (bf16_t)wk2[(h << 13) + (e << 6) + f];
    }
    if (idx < 16 * 64 * 64) {             // [h][g][f] <- [h][f][g]
        int h = idx >> 12, g = (idx >> 6) & 63, f = idx & 63;
        iKt[idx] = (bf16_t)iK[(h << 12) + (f << 6) + g];
    }
}

// ---------------- mask: normalize to uchar [B,S,S] (handles int32 or byte input) --------
__global__ __launch_bounds__(256) void prep_mask_kernel(
    const unsigned char* __restrict__ mask8, unsigned char* __restrict__ mout)
{
    __shared__ int mflag;
    const int tid = threadIdx.x;
    if (tid == 0) {     // int32 storage => bytes 4i+1 all zero over first 64 elems
        unsigned a = 0;
        for (int i = 0; i < 64; ++i) a |= mask8[4 * i + 1];
        mflag = (a == 0) ? 1 : 0;
    }
    __syncthreads();
    const size_t base = ((size_t)blockIdx.x * 256 + tid) * 16;   // 16 bytes out/thread
    if (mflag) {
        const int* mi = (const int*)mask8;
        uint4 r;
        unsigned bs[4];
#pragma unroll
        for (int j = 0; j < 4; ++j) {
            int4 v = *reinterpret_cast<const int4*>(&mi[base + j * 4]);
            bs[j] = (v.x ? 1u : 0u) | ((v.y ? 1u : 0u) << 8) |
                    ((v.z ? 1u : 0u) << 16) | ((v.w ? 1u : 0u) << 24);
        }
        r.x = bs[0]; r.y = bs[1]; r.z = bs[2]; r.w = bs[3];
        *reinterpret_cast<uint4*>(&mout[base]) = r;
    } else {
        uint4 v = *reinterpret_cast<const uint4*>(&mask8[base]);
        uint4 r;
        unsigned* pv = (unsigned*)&v;
        unsigned* pr = (unsigned*)&r;
#pragma unroll
        for (int j = 0; j < 4; ++j) {
            unsigned x = pv[j], o = 0;
#pragma unroll
            for (int k = 0; k < 4; ++k)
                o |= (((x >> (8 * k)) & 255u) ? 1u : 0u) << (8 * k);
            pr[j] = o;
        }
        *reinterpret_cast<uint4*>(&mout[base]) = r;
    }
}

// ---------------- V: [B,S,H,128] f32 -> vT tiled [B,H,tt(16),128,64] bf16 ---------------
__global__ __launch_bounds__(256) void conv_v_kernel(
    const float* __restrict__ v, bf16_t* __restrict__ vT)
{
    __shared__ bf16_t tr[128][72];
    const int bh = blockIdx.x, b = bh >> 4, h = bh & 15;
    const int tt = blockIdx.y;
    const int t0 = tt * 64;
    const int tid = threadIdx.x;
#pragma unroll
    for (int i = 0; i < 8; ++i) {
        int f4 = tid + 256 * i;                 // 2048 float4 = 64 t x 128 d
        int t = f4 >> 5, c4 = f4 & 31;
        const float4 vv = *reinterpret_cast<const float4*>(
            &v[((size_t)b * 1024 + t0 + t) * 2048 + h * 128 + c4 * 4]);
        tr[c4 * 4 + 0][t] = (bf16_t)vv.x;
        tr[c4 * 4 + 1][t] = (bf16_t)vv.y;
        tr[c4 * 4 + 2][t] = (bf16_t)vv.z;
        tr[c4 * 4 + 3][t] = (bf16_t)vv.w;
    }
    __syncthreads();
#pragma unroll
    for (int i = 0; i < 32; ++i) {
        int e = tid + 256 * i;                  // 8192 bf16
        int d = e >> 6, tl = e & 63;
        vT[(((size_t)bh * 16 + tt) * 128 + d) * 64 + tl] = tr[d][tl];
    }
}

// ---------------- feature maps: qf = |gelu(gelu(q W1) W2)|, kf path w/ interaction ------
__global__ __launch_bounds__(256) void feat_kernel(
    const float* __restrict__ q, const float* __restrict__ k,
    const bf16_t* __restrict__ wq1t, const bf16_t* __restrict__ wq2t,
    const bf16_t* __restrict__ wk1t, const bf16_t* __restrict__ wk2t,
    const bf16_t* __restrict__ iKt,
    const float* __restrict__ sD, const float* __restrict__ sD2,
    bf16_t* __restrict__ qf, bf16_t* __restrict__ kf)
{
    __shared__ bf16_t xa[64][136];
    __shared__ bf16_t h1[64][136];
    __shared__ bf16_t k2[64][72];

    const int tid = threadIdx.x;
    const int lane = tid & 63, w = tid >> 6;
    const int lr = lane & 15, lg = lane >> 4;
    const int row0 = blockIdx.x * 64;
    const int h = blockIdx.y;
    const int path = blockIdx.z;               // 0 = q, 1 = k

    const float* X = path ? k : q;
    const bf16_t* w1t = path ? wk1t : wq1t;
    const bf16_t* w2t = path ? wk2t : wq2t;
    bf16_t* outp = path ? kf : qf;

#pragma unroll
    for (int i = 0; i < 8; ++i) {
        int f4 = tid + 256 * i;
        int r = f4 >> 5, c4 = f4 & 31;
        const float4 vv = *reinterpret_cast<const float4*>(
            &X[(size_t)(row0 + r) * 2048 + h * 128 + c4 * 4]);
        xa[r][c4 * 4 + 0] = (bf16_t)vv.x;
        xa[r][c4 * 4 + 1] = (bf16_t)vv.y;
        xa[r][c4 * 4 + 2] = (bf16_t)vv.z;
        xa[r][c4 * 4 + 3] = (bf16_t)vv.w;
    }
    __syncthreads();

    bf16x8 a1[4];
#pragma unroll
    for (int kk = 0; kk < 4; ++kk)
        a1[kk] = *reinterpret_cast<const bf16x8*>(&xa[w * 16 + lr][kk * 32 + lg * 8]);
#pragma unroll
    for (int nt = 0; nt < 8; ++nt) {
        f32x4 acc = {0.f, 0.f, 0.f, 0.f};
#pragma unroll
        for (int kk = 0; kk < 4; ++kk) {
            bf16x8 bfr = *reinterpret_cast<const bf16x8*>(
                &w1t[(size_t)h * 16384 + (nt * 16 + lr) * 128 + kk * 32 + lg * 8]);
            acc = MFMA(a1[kk], bfr, acc);
        }
#pragma unroll
        for (int r = 0; r < 4; ++r)
            h1[w * 16 + lg * 4 + r][nt * 16 + lr] = (bf16_t)gelu_exact(acc[r]);
    }
    __syncthreads();

    bf16x8 a2[4];
#pragma unroll
    for (int kk = 0; kk < 4; ++kk)
        a2[kk] = *reinterpret_cast<const bf16x8*>(&h1[w * 16 + lr][kk * 32 + lg * 8]);

    if (path == 0) {
#pragma unroll
        for (int nt = 0; nt < 4; ++nt) {
            f32x4 acc = {0.f, 0.f, 0.f, 0.f};
#pragma unroll
            for (int kk = 0; kk < 4; ++kk) {
                bf16x8 bfr = *reinterpret_cast<const bf16x8*>(
                    &w2t[(size_t)h * 8192 + (nt * 16 + lr) * 128 + kk * 32 + lg * 8]);
                acc = MFMA(a2[kk], bfr, acc);
            }
#pragma unroll
            for (int r = 0; r < 4; ++r) {
                int n = row0 + w * 16 + lg * 4 + r;
                int bb = n >> 10, s = n & 1023;
                outp[(((size_t)bb * 16 + h) * 1024 + s) * 64 + nt * 16 + lr] =
                    (bf16_t)fabsf(gelu_exact(acc[r]));
            }
        }
    } else {
#pragma unroll
        for (int nt = 0; nt < 4; ++nt) {
            f32x4 acc = {0.f, 0.f, 0.f, 0.f};
#pragma unroll
            for (int kk = 0; kk < 4; ++kk) {
                bf16x8 bfr = *reinterpret_cast<const bf16x8*>(
                    &w2t[(size_t)h * 8192 + (nt * 16 + lr) * 128 + kk * 32 + lg * 8]);
                acc = MFMA(a2[kk], bfr, acc);
            }
#pragma unroll
            for (int r = 0; r < 4; ++r) {
                int f = nt * 16 + lr;
                k2[w * 16 + lg * 4 + r][f] =
                    (bf16_t)(fabsf(sD[h * 64 + f]) * gelu_exact(acc[r]));
            }
        }
        __syncthreads();
        bf16x8 a3[2];
#pragma unroll
        for (int kk = 0; kk < 2; ++kk)
            a3[kk] = *reinterpret_cast<const bf16x8*>(&k2[w * 16 + lr][kk * 32 + lg * 8]);
#pragma unroll
        for (int nt = 0; nt < 4; ++nt) {
            f32x4 acc = {0.f, 0.f, 0.f, 0.f};
#pragma unroll
            for (int kk = 0; kk < 2; ++kk) {
                bf16x8 bfr = *reinterpret_cast<const bf16x8*>(
                    &iKt[(size_t)h * 4096 + (nt * 16 + lr) * 64 + kk * 32 + lg * 8]);
                acc = MFMA(a3[kk], bfr, acc);
            }
#pragma unroll
            for (int r = 0; r < 4; ++r) {
                int row = w * 16 + lg * 4 + r;
                int g = nt * 16 + lr;
                float base = (float)k2[row][g];
                float kv = fabsf(base + acc[r] * sD2[h * 64 + g]);
                int n = row0 + row;
                int bb = n >> 10, s = n & 1023;
                outp[(((size_t)bb * 16 + h) * 1024 + s) * 64 + g] = (bf16_t)kv;
            }
        }
    }
}

// ---------------- fused attention: counted-vmcnt, 2 raw barriers per phase --------------
__global__ __launch_bounds__(256, 3) void attn_cv_kernel(
    const bf16_t* __restrict__ qf, const bf16_t* __restrict__ kf,
    const bf16_t* __restrict__ vT,
    const unsigned char* __restrict__ mprep,
    const float* __restrict__ saw, const float* __restrict__ lse,
    float* __restrict__ out)
{
    __shared__ bf16_t vbuf[2][128 * 64];      // XOR-swizzled V tiles (16KB each)
    __shared__ bf16_t kbuf[2][64 * 64];       // XOR-swizzled K tiles (8KB each)

    const int tid = threadIdx.x;
    const int lane = tid & 63, w = tid >> 6;
    const int lr = lane & 15, lg = lane >> 4;

    // XCD swizzle: all 16 s-blocks of a bh share one XCD's L2
    const int di = blockIdx.y * 16 + blockIdx.x;   // 0..1023
    const int xcd = di & 7, rr = di >> 3;
    const int bh = xcd + 8 * (rr >> 4);
    const int s0 = (rr & 15) * 64;
    const int b = bh >> 4, h = bh & 15;

    const int srow = s0 + w * 16 + lr;             // this lane's single s-row
    const size_t saw_row = ((size_t)bh << 20) + (size_t)srow * 1024;
    const size_t m_row   = ((size_t)b << 20) + (size_t)srow * 1024;

    // staging mapping (inverse-swizzled global source, linear LDS dest)
    const int vrow = tid >> 3;                     // 0..31
    const int vcol8 = (tid & 7) ^ (vrow & 7);
    const bf16_t* vt_bh = vT + (size_t)bh * 131072;
    const bf16_t* kf_bh = kf + (size_t)bh * 65536;

    // Q as B-fragments (n = s, k = f)
    bf16x8 aq0, aq1;
    {
        const size_t qb = ((size_t)bh * 1024 + srow) * 64;
        aq0 = *reinterpret_cast<const bf16x8*>(&qf[qb + lg * 8]);
        aq1 = *reinterpret_cast<const bf16x8*>(&qf[qb + 32 + lg * 8]);
    }

    const f32x4 fzero = {0.f, 0.f, 0.f, 0.f};
    f32x4 oacc[8];
#pragma unroll
    for (int i = 0; i < 8; ++i) oacc[i] = fzero;
    float rs = 0.f;

#define STAGE_VT(BUF, TILE)                                                      \
    {                                                                            \
        const bf16_t* vg = vt_bh + (size_t)(TILE) * 8192 + vcol8 * 8;            \
        char* lb = (char*)&vbuf[BUF][0] + w * 1024;                              \
        _Pragma("unroll")                                                        \
        for (int j = 0; j < 4; ++j)                                              \
            gload16(vg + (size_t)(32 * j + vrow) * 64, lb + j * 4096);           \
    }

#define STAGE_KF(BUF, TILE)                                                      \
    {                                                                            \
        const bf16_t* kg = kf_bh + (size_t)(TILE) * 4096 + vcol8 * 8;            \
        char* lb = (char*)&kbuf[BUF][0] + w * 1024;                              \
        _Pragma("unroll")                                                        \
        for (int j = 0; j < 2; ++j)                                              \
            gload16(kg + (size_t)(32 * j + vrow) * 64, lb + j * 4096);           \
    }

#define LOAD_SAW(TILE, SS, MM)                                                   \
    {                                                                            \
        _Pragma("unroll")                                                        \
        for (int nt = 0; nt < 4; ++nt) {                                         \
            SS[nt] = *reinterpret_cast<const f32x4*>(                            \
                &saw[saw_row + (size_t)(TILE) * 64 + nt * 16 + lg * 4]);         \
            MM[nt] = *reinterpret_cast<const unsigned*>(                         \
                &mprep[m_row + (size_t)(TILE) * 64 + nt * 16 + lg * 4]);         \
        }                                                                        \
    }

// QK^T from swizzled kbuf + register merge -> pk[8] (bf16 pairs), rowsum rs
#define QKT_MERGE(CUR, SS, MM)                                                   \
    {                                                                            \
        _Pragma("unroll")                                                        \
        for (int nt = 0; nt < 4; ++nt) {                                         \
            const int row = nt * 16 + lr;                                        \
            const char* kb = (const char*)&kbuf[CUR][0] + row * 128;             \
            const int sw = (row & 7) * 16;                                       \
            bf16x8 k0 = *reinterpret_cast<const bf16x8*>(kb + ((lg * 16) ^ sw)); \
            bf16x8 k1 = *reinterpret_cast<const bf16x8*>(kb + ((64 + lg * 16) ^ sw)); \
            f32x4 acc = fzero;                                                   \
            acc = MFMA(k0, aq0, acc);                                            \
            acc = MFMA(k1, aq1, acc);                                            \
            const unsigned mm = MM[nt];                                          \
            float v0, v1, v2, v3;                                                \
            v0 = (mm & 255u)         ? (acc[0] + 1e-6f) : __expf(SS[nt][0]);     \
            rs += (mm & 255u)         ? acc[0] : 0.f;                            \
            v1 = ((mm >> 8) & 255u)  ? (acc[1] + 1e-6f) : __expf(SS[nt][1]);     \
            rs += ((mm >> 8) & 255u)  ? acc[1] : 0.f;                            \
            v2 = ((mm >> 16) & 255u) ? (acc[2] + 1e-6f) : __expf(SS[nt][2]);     \
            rs += ((mm >> 16) & 255u) ? acc[2] : 0.f;                            \
            v3 = (mm >> 24)          ? (acc[3] + 1e-6f) : __expf(SS[nt][3]);     \
            rs += (mm >> 24)          ? acc[3] : 0.f;                            \
            pk[nt * 2]     = pack_bf16(v0, v1);                                  \
            pk[nt * 2 + 1] = pack_bf16(v2, v3);                                  \
        }                                                                        \
    }

// redistribute P across the 4 lanes sharing lr -> PV B-fragments.
// ALL shuffles run at full EXEC (no control dependence); selection is a pure
// cndmask on the shuffled values (R8's divergent-ternary shfl was the bug).
#define REDIST()                                                                 \
    {                                                                            \
        const int srcA = lr + ((lg & 1) << 5);                                   \
        const int srcB = srcA + 16;                                              \
        const bool sel = (lg < 2);                                               \
        const unsigned a0 = __shfl(pk[0], srcA, 64);                             \
        const unsigned a1 = __shfl(pk[1], srcA, 64);                             \
        const unsigned a2 = __shfl(pk[2], srcA, 64);                             \
        const unsigned a3 = __shfl(pk[3], srcA, 64);                             \
        const unsigned b0 = __shfl(pk[0], srcB, 64);                             \
        const unsigned b1 = __shfl(pk[1], srcB, 64);                             \
        const unsigned b2 = __shfl(pk[2], srcB, 64);                             \
        const unsigned b3 = __shfl(pk[3], srcB, 64);                             \
        f0w.x = sel ? a0 : a2;  f0w.y = sel ? a1 : a3;                           \
        f0w.z = sel ? b0 : b2;  f0w.w = sel ? b1 : b3;                           \
        const unsigned c4 = __shfl(pk[4], srcA, 64);                             \
        const unsigned c5 = __shfl(pk[5], srcA, 64);                             \
        const unsigned c6 = __shfl(pk[6], srcA, 64);                             \
        const unsigned c7 = __shfl(pk[7], srcA, 64);                             \
        const unsigned d4 = __shfl(pk[4], srcB, 64);                             \
        const unsigned d5 = __shfl(pk[5], srcB, 64);                             \
        const unsigned d6 = __shfl(pk[6], srcB, 64);                             \
        const unsigned d7 = __shfl(pk[7], srcB, 64);                             \
        f1w.x = sel ? c4 : c6;  f1w.y = sel ? c5 : c7;                           \
        f1w.z = sel ? d4 : d6;  f1w.w = sel ? d5 : d7;                           \
    }

#define PV(CUR)                                                                  \
    {                                                                            \
        bf16x8 pf0 = __builtin_bit_cast(bf16x8, f0w);                            \
        bf16x8 pf1 = __builtin_bit_cast(bf16x8, f1w);                            \
        _Pragma("unroll")                                                        \
        for (int dt = 0; dt < 8; ++dt) {                                         \
            const int row = dt * 16 + lr;                                        \
            const char* vb = (const char*)&vbuf[CUR][0] + row * 128;             \
            const int sw = (row & 7) * 16;                                       \
            bf16x8 v0 = *reinterpret_cast<const bf16x8*>(vb + ((lg * 16) ^ sw)); \
            bf16x8 v1 = *reinterpret_cast<const bf16x8*>(vb + ((64 + lg * 16) ^ sw)); \
            oacc[dt] = MFMA(v0, pf0, oacc[dt]);                                  \
            oacc[dt] = MFMA(v1, pf1, oacc[dt]);                                  \
        }                                                                        \
    }

// one full phase: stage(i+1) -> counted wait -> barrier -> compute(i) -> barrier
#define FULL_PHASE(CUR, NXT, TN1, SS, MM, TN2)                                   \
    {                                                                            \
        STAGE_VT(NXT, TN1);                                                      \
        STAGE_KF(NXT, TN1);                                                      \
        __builtin_amdgcn_sched_barrier(0);                                       \
        asm volatile("s_waitcnt vmcnt(14)" ::: "memory");                        \
        __builtin_amdgcn_s_barrier();                                            \
        __builtin_amdgcn_sched_barrier(0);                                       \
        QKT_MERGE(CUR, SS, MM);                                                  \
        REDIST();                                                                \
        LOAD_SAW(TN2, SS, MM);                                                   \
        __builtin_amdgcn_sched_barrier(0);                                       \
        PV(CUR);                                                                 \
        __builtin_amdgcn_sched_barrier(0);                                       \
        __builtin_amdgcn_s_barrier();                                            \
    }

    f32x4 sawA[4], sawB[4];
    unsigned muA[4], muB[4];
    unsigned pk[8];
    uint4 f0w, f1w;

    // ---- prologue: stage tile 0; saw tiles 0 and 1 (depth 2)
    STAGE_VT(0, 0);
    STAGE_KF(0, 0);
    LOAD_SAW(0, sawA, muA);
    LOAD_SAW(1, sawB, muB);

    for (int i = 0; i < 16; i += 2) {
        FULL_PHASE(0, 1, i + 1,          sawA, muA, (i + 2) & 15);
        FULL_PHASE(1, 0, (i + 2) & 15,   sawB, muB, (i + 3) & 15);
    }

    // rowsum: sum the 4 lg-partials for this s-row
    rs += __shfl_xor(rs, 16);
    rs += __shfl_xor(rs, 32);
    const float invden =
        1.0f / (rs + 1e-6f + __expf(lse[(size_t)bh * 1024 + srow]));

    const size_t ob = ((size_t)b * 1024 + srow) * 2048 + h * 128 + lg * 4;
#pragma unroll
    for (int dt = 0; dt < 8; ++dt) {
        f32x4 o;
        o[0] = oacc[dt][0] * invden;
        o[1] = oacc[dt][1] * invden;
        o[2] = oacc[dt][2] * invden;
        o[3] = oacc[dt][3] * invden;
        *reinterpret_cast<f32x4*>(&out[ob + dt * 16]) = o;
    }
#undef STAGE_VT
#undef STAGE_KF
#undef LOAD_SAW
#undef QKT_MERGE
#undef REDIST
#undef PV
#undef FULL_PHASE
}

extern "C" void kernel_launch(void* const* d_in, const int* in_sizes, int n_in,
                              void* d_out, int out_size, void* d_ws, size_t ws_size,
                              hipStream_t stream)
{
    const float* q   = (const float*)d_in[0];
    const float* k   = (const float*)d_in[1];
    const float* v   = (const float*)d_in[2];
    const unsigned char* mask = (const unsigned char*)d_in[3];
    const float* lse = (const float*)d_in[4];
    const float* saw = (const float*)d_in[5];
    const float* wq1 = (const float*)d_in[6];
    const float* wk1 = (const float*)d_in[7];
    const float* wq2 = (const float*)d_in[8];
    const float* wk2 = (const float*)d_in[9];
    const float* iK  = (const float*)d_in[10];
    const float* sD  = (const float*)d_in[11];
    const float* sD2 = (const float*)d_in[12];
    float* out = (float*)d_out;

    bf16_t* wsb  = (bf16_t*)d_ws;
    bf16_t* wq1t = wsb;                    // 16*128*128 = 262144
    bf16_t* wk1t = wq1t + 262144;
    bf16_t* wq2t = wk1t + 262144;          // 16*64*128 = 131072
    bf16_t* wk2t = wq2t + 131072;
    bf16_t* iKt  = wk2t + 131072;          // 16*64*64  = 65536
    bf16_t* qf   = iKt  + 65536;           // 4*16*1024*64 = 4194304
    bf16_t* kf   = qf   + 4194304;
    bf16_t* vT   = kf   + 4194304;         // 4*16*128*1024 = 8388608 (tiled)
    unsigned char* mprep = (unsigned char*)(vT + 8388608);  // 4MB uchar [B,S,S]
    // total ws use: ~39.3 MB

    conv_weights_kernel<<<dim3(1024), dim3(256), 0, stream>>>(
        wq1, wk1, wq2, wk2, iK, wq1t, wk1t, wq2t, wk2t, iKt);
    prep_mask_kernel<<<dim3(1024), dim3(256), 0, stream>>>(mask, mprep);
    conv_v_kernel<<<dim3(64, 16), dim3(256), 0, stream>>>(v, vT);
    feat_kernel<<<dim3(64, 16, 2), dim3(256), 0, stream>>>(
        q, k, wq1t, wq2t, wk1t, wk2t, iKt, sD, sD2, qf, kf);
    attn_cv_kernel<<<dim3(16, 64), dim3(256), 0, stream>>>(
        qf, kf, vT, mprep, saw, lse, out);
}

// Round 10
// 197.813 us; speedup vs baseline: 1.2677x; 1.0540x over previous
//
#include <hip/hip_runtime.h>

// KernelizedHeadAttention, B=4 S=1024 D=2048 H=16 DH=128 DHID=128 DKER=64
// out[s] = [ sum_t (m? score+eps : exp(saw)) * v[t] ] / (rowsum_s + eps + exp(lse_s))
// R10 = R9 (counted-vmcnt, swapped QK^T, full-EXEC shfl REDIST) with the pipeline
// deepened to stage-depth-2: triple-buffered vbuf/kbuf, phase i stages tile i+2,
// steady-state s_waitcnt vmcnt(28) (exact count of newer ops), peeled epilogue with
// vmcnt(22)/vmcnt(8). WAR safe: stage(i+2) writes buf (i-1)%3 whose readers finished
// before end-barrier(i-1). + T5 setprio around PV MFMA cluster. LDS 72KB -> 2 blk/CU.

typedef __bf16 bf16_t;
typedef __attribute__((ext_vector_type(8))) __bf16 bf16x8;
typedef __attribute__((ext_vector_type(4))) float f32x4;

#define MFMA(a, b, c) __builtin_amdgcn_mfma_f32_16x16x32_bf16((a), (b), (c), 0, 0, 0)

typedef __attribute__((address_space(3))) void as3_void;
typedef __attribute__((address_space(1))) const void as1_void;
static __device__ __forceinline__ void gload16(const void* g, void* l) {
    __builtin_amdgcn_global_load_lds((as1_void*)g, (as3_void*)l, 16, 0, 0);
}

static __device__ __forceinline__ float gelu_exact(float x) {
    return 0.5f * x * (1.0f + erff(x * 0.70710678118654752f));
}

static __device__ __forceinline__ unsigned pack_bf16(float a, float b) {
    bf16_t x = (bf16_t)a, y = (bf16_t)b;
    unsigned short ux = __builtin_bit_cast(unsigned short, x);
    unsigned short uy = __builtin_bit_cast(unsigned short, y);
    return (unsigned)ux | ((unsigned)uy << 16);
}

// ---------------- weights: convert f32 -> bf16, transposed for B-fragments ----------------
__global__ __launch_bounds__(256) void conv_weights_kernel(
    const float* __restrict__ wq1, const float* __restrict__ wk1,
    const float* __restrict__ wq2, const float* __restrict__ wk2,
    const float* __restrict__ iK,
    bf16_t* __restrict__ wq1t, bf16_t* __restrict__ wk1t,
    bf16_t* __restrict__ wq2t, bf16_t* __restrict__ wk2t,
    bf16_t* __restrict__ iKt)
{
    const int idx = blockIdx.x * 256 + threadIdx.x;
    if (idx < 16 * 128 * 128) {           // [h][e][d] <- [h][d][e]
        int h = idx >> 14, e = (idx >> 7) & 127, d = idx & 127;
        wq1t[idx] = (bf16_t)wq1[(h << 14) + (d << 7) + e];
        wk1t[idx] = (bf16_t)wk1[(h << 14) + (d << 7) + e];
    }
    if (idx < 16 * 64 * 128) {            // [h][f][e] <- [h][e][f]
        int h = idx >> 13, f = (idx >> 7) & 63, e = idx & 127;
        wq2t[idx] = (bf16_t)wq2[(h << 13) + (e << 6) + f];
        wk2t[idx] = (bf16_t)wk2[(h << 13) + (e << 6) + f];
    }
    if (idx < 16 * 64 * 64) {             // [h][g][f] <- [h][f][g]
        int h = idx >> 12, g = (idx >> 6) & 63, f = idx & 63;
        iKt[idx] = (bf16_t)iK[(h << 12) + (f << 6) + g];
    }
}

// ---------------- mask: normalize to uchar [B,S,S] (handles int32 or byte input) --------
__global__ __launch_bounds__(256) void prep_mask_kernel(
    const unsigned char* __restrict__ mask8, unsigned char* __restrict__ mout)
{
    __shared__ int mflag;
    const int tid = threadIdx.x;
    if (tid == 0) {     // int32 storage => bytes 4i+1 all zero over first 64 elems
        unsigned a = 0;
        for (int i = 0; i < 64; ++i) a |= mask8[4 * i + 1];
        mflag = (a == 0) ? 1 : 0;
    }
    __syncthreads();
    const size_t base = ((size_t)blockIdx.x * 256 + tid) * 16;   // 16 bytes out/thread
    if (mflag) {
        const int* mi = (const int*)mask8;
        uint4 r;
        unsigned bs[4];
#pragma unroll
        for (int j = 0; j < 4; ++j) {
            int4 v = *reinterpret_cast<const int4*>(&mi[base + j * 4]);
            bs[j] = (v.x ? 1u : 0u) | ((v.y ? 1u : 0u) << 8) |
                    ((v.z ? 1u : 0u) << 16) | ((v.w ? 1u : 0u) << 24);
        }
        r.x = bs[0]; r.y = bs[1]; r.z = bs[2]; r.w = bs[3];
        *reinterpret_cast<uint4*>(&mout[base]) = r;
    } else {
        uint4 v = *reinterpret_cast<const uint4*>(&mask8[base]);
        uint4 r;
        unsigned* pv = (unsigned*)&v;
        unsigned* pr = (unsigned*)&r;
#pragma unroll
        for (int j = 0; j < 4; ++j) {
            unsigned x = pv[j], o = 0;
#pragma unroll
            for (int k = 0; k < 4; ++k)
                o |= (((x >> (8 * k)) & 255u) ? 1u : 0u) << (8 * k);
            pr[j] = o;
        }
        *reinterpret_cast<uint4*>(&mout[base]) = r;
    }
}

// ---------------- V: [B,S,H,128] f32 -> vT tiled [B,H,tt(16),128,64] bf16 ---------------
__global__ __launch_bounds__(256) void conv_v_kernel(
    const float* __restrict__ v, bf16_t* __restrict__ vT)
{
    __shared__ bf16_t tr[128][72];
    const int bh = blockIdx.x, b = bh >> 4, h = bh & 15;
    const int tt = blockIdx.y;
    const int t0 = tt * 64;
    const int tid = threadIdx.x;
#pragma unroll
    for (int i = 0; i < 8; ++i) {
        int f4 = tid + 256 * i;                 // 2048 float4 = 64 t x 128 d
        int t = f4 >> 5, c4 = f4 & 31;
        const float4 vv = *reinterpret_cast<const float4*>(
            &v[((size_t)b * 1024 + t0 + t) * 2048 + h * 128 + c4 * 4]);
        tr[c4 * 4 + 0][t] = (bf16_t)vv.x;
        tr[c4 * 4 + 1][t] = (bf16_t)vv.y;
        tr[c4 * 4 + 2][t] = (bf16_t)vv.z;
        tr[c4 * 4 + 3][t] = (bf16_t)vv.w;
    }
    __syncthreads();
#pragma unroll
    for (int i = 0; i < 32; ++i) {
        int e = tid + 256 * i;                  // 8192 bf16
        int d = e >> 6, tl = e & 63;
        vT[(((size_t)bh * 16 + tt) * 128 + d) * 64 + tl] = tr[d][tl];
    }
}

// ---------------- feature maps: qf = |gelu(gelu(q W1) W2)|, kf path w/ interaction ------
__global__ __launch_bounds__(256) void feat_kernel(
    const float* __restrict__ q, const float* __restrict__ k,
    const bf16_t* __restrict__ wq1t, const bf16_t* __restrict__ wq2t,
    const bf16_t* __restrict__ wk1t, const bf16_t* __restrict__ wk2t,
    const bf16_t* __restrict__ iKt,
    const float* __restrict__ sD, const float* __restrict__ sD2,
    bf16_t* __restrict__ qf, bf16_t* __restrict__ kf)
{
    __shared__ bf16_t xa[64][136];
    __shared__ bf16_t h1[64][136];
    __shared__ bf16_t k2[64][72];

    const int tid = threadIdx.x;
    const int lane = tid & 63, w = tid >> 6;
    const int lr = lane & 15, lg = lane >> 4;
    const int row0 = blockIdx.x * 64;
    const int h = blockIdx.y;
    const int path = blockIdx.z;               // 0 = q, 1 = k

    const float* X = path ? k : q;
    const bf16_t* w1t = path ? wk1t : wq1t;
    const bf16_t* w2t = path ? wk2t : wq2t;
    bf16_t* outp = path ? kf : qf;

#pragma unroll
    for (int i = 0; i < 8; ++i) {
        int f4 = tid + 256 * i;
        int r = f4 >> 5, c4 = f4 & 31;
        const float4 vv = *reinterpret_cast<const float4*>(
            &X[(size_t)(row0 + r) * 2048 + h * 128 + c4 * 4]);
        xa[r][c4 * 4 + 0] = (bf16_t)vv.x;
        xa[r][c4 * 4 + 1] = (bf16_t)vv.y;
        xa[r][c4 * 4 + 2] = (bf16_t)vv.z;
        xa[r][c4 * 4 + 3] = (bf16_t)vv.w;
    }
    __syncthreads();

    bf16x8 a1[4];
#pragma unroll
    for (int kk = 0; kk < 4; ++kk)
        a1[kk] = *reinterpret_cast<const bf16x8*>(&xa[w * 16 + lr][kk * 32 + lg * 8]);
#pragma unroll
    for (int nt = 0; nt < 8; ++nt) {
        f32x4 acc = {0.f, 0.f, 0.f, 0.f};
#pragma unroll
        for (int kk = 0; kk < 4; ++kk) {
            bf16x8 bfr = *reinterpret_cast<const bf16x8*>(
                &w1t[(size_t)h * 16384 + (nt * 16 + lr) * 128 + kk * 32 + lg * 8]);
            acc = MFMA(a1[kk], bfr, acc);
        }
#pragma unroll
        for (int r = 0; r < 4; ++r)
            h1[w * 16 + lg * 4 + r][nt * 16 + lr] = (bf16_t)gelu_exact(acc[r]);
    }
    __syncthreads();

    bf16x8 a2[4];
#pragma unroll
    for (int kk = 0; kk < 4; ++kk)
        a2[kk] = *reinterpret_cast<const bf16x8*>(&h1[w * 16 + lr][kk * 32 + lg * 8]);

    if (path == 0) {
#pragma unroll
        for (int nt = 0; nt < 4; ++nt) {
            f32x4 acc = {0.f, 0.f, 0.f, 0.f};
#pragma unroll
            for (int kk = 0; kk < 4; ++kk) {
                bf16x8 bfr = *reinterpret_cast<const bf16x8*>(
                    &w2t[(size_t)h * 8192 + (nt * 16 + lr) * 128 + kk * 32 + lg * 8]);
                acc = MFMA(a2[kk], bfr, acc);
            }
#pragma unroll
            for (int r = 0; r < 4; ++r) {
                int n = row0 + w * 16 + lg * 4 + r;
                int bb = n >> 10, s = n & 1023;
                outp[(((size_t)bb * 16 + h) * 1024 + s) * 64 + nt * 16 + lr] =
                    (bf16_t)fabsf(gelu_exact(acc[r]));
            }
        }
    } else {
#pragma unroll
        for (int nt = 0; nt < 4; ++nt) {
            f32x4 acc = {0.f, 0.f, 0.f, 0.f};
#pragma unroll
            for (int kk = 0; kk < 4; ++kk) {
                bf16x8 bfr = *reinterpret_cast<const bf16x8*>(
                    &w2t[(size_t)h * 8192 + (nt * 16 + lr) * 128 + kk * 32 + lg * 8]);
                acc = MFMA(a2[kk], bfr, acc);
            }
#pragma unroll
            for (int r = 0; r < 4; ++r) {
                int f = nt * 16 + lr;
                k2[w * 16 + lg * 4 + r][f] =
                    (bf16_t)(fabsf(sD[h * 64 + f]) * gelu_exact(acc[r]));
            }
        }
        __syncthreads();
        bf16x8 a3[2];
#pragma unroll
        for (int kk = 0; kk < 2; ++kk)
            a3[kk] = *reinterpret_cast<const bf16x8*>(&k2[w * 16 + lr][kk * 32 + lg * 8]);
#pragma unroll
        for (int nt = 0; nt < 4; ++nt) {
            f32x4 acc = {0.f, 0.f, 0.f, 0.f};
#pragma unroll
            for (int kk = 0; kk < 2; ++kk) {
                bf16x8 bfr = *reinterpret_cast<const bf16x8*>(
                    &iKt[(size_t)h * 4096 + (nt * 16 + lr) * 64 + kk * 32 + lg * 8]);
                acc = MFMA(a3[kk], bfr, acc);
            }
#pragma unroll
            for (int r = 0; r < 4; ++r) {
                int row = w * 16 + lg * 4 + r;
                int g = nt * 16 + lr;
                float base = (float)k2[row][g];
                float kv = fabsf(base + acc[r] * sD2[h * 64 + g]);
                int n = row0 + row;
                int bb = n >> 10, s = n & 1023;
                outp[(((size_t)bb * 16 + h) * 1024 + s) * 64 + g] = (bf16_t)kv;
            }
        }
    }
}

// ---------------- fused attention: depth-2 staging, triple-buffer, counted vmcnt --------
__global__ __launch_bounds__(256, 2) void attn_cv_kernel(
    const bf16_t* __restrict__ qf, const bf16_t* __restrict__ kf,
    const bf16_t* __restrict__ vT,
    const unsigned char* __restrict__ mprep,
    const float* __restrict__ saw, const float* __restrict__ lse,
    float* __restrict__ out)
{
    __shared__ bf16_t vbuf[3][128 * 64];      // XOR-swizzled V tiles (16KB each)
    __shared__ bf16_t kbuf[3][64 * 64];       // XOR-swizzled K tiles (8KB each)

    const int tid = threadIdx.x;
    const int lane = tid & 63, w = tid >> 6;
    const int lr = lane & 15, lg = lane >> 4;

    // XCD swizzle: all 16 s-blocks of a bh share one XCD's L2
    const int di = blockIdx.y * 16 + blockIdx.x;   // 0..1023
    const int xcd = di & 7, rr = di >> 3;
    const int bh = xcd + 8 * (rr >> 4);
    const int s0 = (rr & 15) * 64;
    const int b = bh >> 4, h = bh & 15;

    const int srow = s0 + w * 16 + lr;             // this lane's single s-row
    const size_t saw_row = ((size_t)bh << 20) + (size_t)srow * 1024;
    const size_t m_row   = ((size_t)b << 20) + (size_t)srow * 1024;

    // staging mapping (inverse-swizzled global source, linear LDS dest)
    const int vrow = tid >> 3;                     // 0..31
    const int vcol8 = (tid & 7) ^ (vrow & 7);
    const bf16_t* vt_bh = vT + (size_t)bh * 131072;
    const bf16_t* kf_bh = kf + (size_t)bh * 65536;

    // Q as B-fragments (n = s, k = f)
    bf16x8 aq0, aq1;
    {
        const size_t qb = ((size_t)bh * 1024 + srow) * 64;
        aq0 = *reinterpret_cast<const bf16x8*>(&qf[qb + lg * 8]);
        aq1 = *reinterpret_cast<const bf16x8*>(&qf[qb + 32 + lg * 8]);
    }

    const f32x4 fzero = {0.f, 0.f, 0.f, 0.f};
    f32x4 oacc[8];
#pragma unroll
    for (int i = 0; i < 8; ++i) oacc[i] = fzero;
    float rs = 0.f;

#define STAGE_VT(BUF, TILE)                                                      \
    {                                                                            \
        const bf16_t* vg = vt_bh + (size_t)(TILE) * 8192 + vcol8 * 8;            \
        char* lb = (char*)&vbuf[BUF][0] + w * 1024;                              \
        _Pragma("unroll")                                                        \
        for (int j = 0; j < 4; ++j)                                              \
            gload16(vg + (size_t)(32 * j + vrow) * 64, lb + j * 4096);           \
    }

#define STAGE_KF(BUF, TILE)                                                      \
    {                                                                            \
        const bf16_t* kg = kf_bh + (size_t)(TILE) * 4096 + vcol8 * 8;            \
        char* lb = (char*)&kbuf[BUF][0] + w * 1024;                              \
        _Pragma("unroll")                                                        \
        for (int j = 0; j < 2; ++j)                                              \
            gload16(kg + (size_t)(32 * j + vrow) * 64, lb + j * 4096);           \
    }

#define LOAD_SAW(TILE, SS, MM)                                                   \
    {                                                                            \
        _Pragma("unroll")                                                        \
        for (int nt = 0; nt < 4; ++nt) {                                         \
            SS[nt] = *reinterpret_cast<const f32x4*>(                            \
                &saw[saw_row + (size_t)(TILE) * 64 + nt * 16 + lg * 4]);         \
            MM[nt] = *reinterpret_cast<const unsigned*>(                         \
                &mprep[m_row + (size_t)(TILE) * 64 + nt * 16 + lg * 4]);         \
        }                                                                        \
    }

// QK^T from swizzled kbuf + register merge -> pk[8] (bf16 pairs), rowsum rs
#define QKT_MERGE(CUR, SS, MM)                                                   \
    {                                                                            \
        _Pragma("unroll")                                                        \
        for (int nt = 0; nt < 4; ++nt) {                                         \
            const int row = nt * 16 + lr;                                        \
            const char* kb = (const char*)&kbuf[CUR][0] + row * 128;             \
            const int sw = (row & 7) * 16;                                       \
            bf16x8 k0 = *reinterpret_cast<const bf16x8*>(kb + ((lg * 16) ^ sw)); \
            bf16x8 k1 = *reinterpret_cast<const bf16x8*>(kb + ((64 + lg * 16) ^ sw)); \
            f32x4 acc = fzero;                                                   \
            acc = MFMA(k0, aq0, acc);                                            \
            acc = MFMA(k1, aq1, acc);                                            \
            const unsigned mm = MM[nt];                                          \
            float v0, v1, v2, v3;                                                \
            v0 = (mm & 255u)         ? (acc[0] + 1e-6f) : __expf(SS[nt][0]);     \
            rs += (mm & 255u)         ? acc[0] : 0.f;                            \
            v1 = ((mm >> 8) & 255u)  ? (acc[1] + 1e-6f) : __expf(SS[nt][1]);     \
            rs += ((mm >> 8) & 255u)  ? acc[1] : 0.f;                            \
            v2 = ((mm >> 16) & 255u) ? (acc[2] + 1e-6f) : __expf(SS[nt][2]);     \
            rs += ((mm >> 16) & 255u) ? acc[2] : 0.f;                            \
            v3 = (mm >> 24)          ? (acc[3] + 1e-6f) : __expf(SS[nt][3]);     \
            rs += (mm >> 24)          ? acc[3] : 0.f;                            \
            pk[nt * 2]     = pack_bf16(v0, v1);                                  \
            pk[nt * 2 + 1] = pack_bf16(v2, v3);                                  \
        }                                                                        \
    }

// redistribute P across the 4 lanes sharing lr -> PV B-fragments.
// ALL shuffles at full EXEC; selection is a pure cndmask on shuffled values.
#define REDIST()                                                                 \
    {                                                                            \
        const int srcA = lr + ((lg & 1) << 5);                                   \
        const int srcB = srcA + 16;                                              \
        const bool sel = (lg < 2);                                               \
        const unsigned a0 = __shfl(pk[0], srcA, 64);                             \
        const unsigned a1 = __shfl(pk[1], srcA, 64);                             \
        const unsigned a2 = __shfl(pk[2], srcA, 64);                             \
        const unsigned a3 = __shfl(pk[3], srcA, 64);                             \
        const unsigned b0 = __shfl(pk[0], srcB, 64);                             \
        const unsigned b1 = __shfl(pk[1], srcB, 64);                             \
        const unsigned b2 = __shfl(pk[2], srcB, 64);                             \
        const unsigned b3 = __shfl(pk[3], srcB, 64);                             \
        f0w.x = sel ? a0 : a2;  f0w.y = sel ? a1 : a3;                           \
        f0w.z = sel ? b0 : b2;  f0w.w = sel ? b1 : b3;                           \
        const unsigned c4 = __shfl(pk[4], srcA, 64);                             \
        const unsigned c5 = __shfl(pk[5], srcA, 64);                             \
        const unsigned c6 = __shfl(pk[6], srcA, 64);                             \
        const unsigned c7 = __shfl(pk[7], srcA, 64);                             \
        const unsigned d4 = __shfl(pk[4], srcB, 64);                             \
        const unsigned d5 = __shfl(pk[5], srcB, 64);                             \
        const unsigned d6 = __shfl(pk[6], srcB, 64);                             \
        const unsigned d7 = __shfl(pk[7], srcB, 64);                             \
        f1w.x = sel ? c4 : c6;  f1w.y = sel ? c5 : c7;                           \
        f1w.z = sel ? d4 : d6;  f1w.w = sel ? d5 : d7;                           \
    }

#define PV(CUR)                                                                  \
    {                                                                            \
        bf16x8 pf0 = __builtin_bit_cast(bf16x8, f0w);                            \
        bf16x8 pf1 = __builtin_bit_cast(bf16x8, f1w);                            \
        __builtin_amdgcn_s_setprio(1);                                           \
        _Pragma("unroll")                                                        \
        for (int dt = 0; dt < 8; ++dt) {                                         \
            const int row = dt * 16 + lr;                                        \
            const char* vb = (const char*)&vbuf[CUR][0] + row * 128;             \
            const int sw = (row & 7) * 16;                                       \
            bf16x8 v0 = *reinterpret_cast<const bf16x8*>(vb + ((lg * 16) ^ sw)); \
            bf16x8 v1 = *reinterpret_cast<const bf16x8*>(vb + ((64 + lg * 16) ^ sw)); \
            oacc[dt] = MFMA(v0, pf0, oacc[dt]);                                  \
            oacc[dt] = MFMA(v1, pf1, oacc[dt]);                                  \
        }                                                                        \
        __builtin_amdgcn_s_setprio(0);                                           \
    }

// one phase: stage(i+2) -> counted wait for stage(i) -> barrier -> compute(i) -> barrier
#define FULL_PHASE(CIDX, SIDX, TSTAGE, SS, MM, TSAW)                             \
    {                                                                            \
        STAGE_VT(SIDX, TSTAGE);                                                  \
        STAGE_KF(SIDX, TSTAGE);                                                  \
        __builtin_amdgcn_sched_barrier(0);                                       \
        asm volatile("s_waitcnt vmcnt(28)" ::: "memory");                        \
        __builtin_amdgcn_s_barrier();                                            \
        __builtin_amdgcn_sched_barrier(0);                                       \
        QKT_MERGE(CIDX, SS, MM);                                                 \
        REDIST();                                                                \
        LOAD_SAW(TSAW, SS, MM);                                                  \
        __builtin_amdgcn_sched_barrier(0);                                       \
        PV(CIDX);                                                                \
        __builtin_amdgcn_sched_barrier(0);                                       \
        __builtin_amdgcn_s_barrier();                                            \
    }

    f32x4 sawA[4], sawB[4];
    unsigned muA[4], muB[4];
    unsigned pk[8];
    uint4 f0w, f1w;

    // ---- prologue: stage tiles 0,1 (bufs 0,1); saw tiles 0,1 (depth 2)
    STAGE_VT(0, 0);
    STAGE_KF(0, 0);
    LOAD_SAW(0, sawA, muA);
    STAGE_VT(1, 1);
    STAGE_KF(1, 1);
    LOAD_SAW(1, sawB, muB);

    int c0 = 0, c1 = 1, c2 = 2;
    // main loop: phases 0..13 (each iteration = 2 phases; phase i stages tile i+2)
    for (int i = 0; i < 14; i += 2) {
        FULL_PHASE(c0, c2, i + 2, sawA, muA, i + 2);        // phase i
        FULL_PHASE(c1, c0, i + 3, sawB, muB, i + 3);        // phase i+1
        const int t_ = c0; c0 = c2; c2 = c1; c1 = t_;       // rotate
    }
    // after 7 rotations: c0 = buf of tile 14, c1 = buf of tile 15

    // peeled phase 14: no staging; stage(14) has 22 newer ops (saw14:8+stage15:6+saw15:8)
    {
        asm volatile("s_waitcnt vmcnt(22)" ::: "memory");
        __builtin_amdgcn_s_barrier();
        __builtin_amdgcn_sched_barrier(0);
        QKT_MERGE(c0, sawA, muA);
        REDIST();
        __builtin_amdgcn_sched_barrier(0);
        PV(c0);
        __builtin_amdgcn_sched_barrier(0);
        __builtin_amdgcn_s_barrier();
    }
    // peeled phase 15: stage(15) has 8 newer ops (saw15)
    {
        asm volatile("s_waitcnt vmcnt(8)" ::: "memory");
        __builtin_amdgcn_s_barrier();
        __builtin_amdgcn_sched_barrier(0);
        QKT_MERGE(c1, sawB, muB);
        REDIST();
        __builtin_amdgcn_sched_barrier(0);
        PV(c1);
    }

    // rowsum: sum the 4 lg-partials for this s-row
    rs += __shfl_xor(rs, 16);
    rs += __shfl_xor(rs, 32);
    const float invden =
        1.0f / (rs + 1e-6f + __expf(lse[(size_t)bh * 1024 + srow]));

    const size_t ob = ((size_t)b * 1024 + srow) * 2048 + h * 128 + lg * 4;
#pragma unroll
    for (int dt = 0; dt < 8; ++dt) {
        f32x4 o;
        o[0] = oacc[dt][0] * invden;
        o[1] = oacc[dt][1] * invden;
        o[2] = oacc[dt][2] * invden;
        o[3] = oacc[dt][3] * invden;
        *reinterpret_cast<f32x4*>(&out[ob + dt * 16]) = o;
    }
#undef STAGE_VT
#undef STAGE_KF
#undef LOAD_SAW
#undef QKT_MERGE
#undef REDIST
#undef PV
#undef FULL_PHASE
}

extern "C" void kernel_launch(void* const* d_in, const int* in_sizes, int n_in,
                              void* d_out, int out_size, void* d_ws, size_t ws_size,
                              hipStream_t stream)
{
    const float* q   = (const float*)d_in[0];
    const float* k   = (const float*)d_in[1];
    const float* v   = (const float*)d_in[2];
    const unsigned char* mask = (const unsigned char*)d_in[3];
    const float* lse = (const float*)d_in[4];
    const float* saw = (const float*)d_in[5];
    const float* wq1 = (const float*)d_in[6];
    const float* wk1 = (const float*)d_in[7];
    const float* wq2 = (const float*)d_in[8];
    const float* wk2 = (const float*)d_in[9];
    const float* iK  = (const float*)d_in[10];
    const float* sD  = (const float*)d_in[11];
    const float* sD2 = (const float*)d_in[12];
    float* out = (float*)d_out;

    bf16_t* wsb  = (bf16_t*)d_ws;
    bf16_t* wq1t = wsb;                    // 16*128*128 = 262144
    bf16_t* wk1t = wq1t + 262144;
    bf16_t* wq2t = wk1t + 262144;          // 16*64*128 = 131072
    bf16_t* wk2t = wq2t + 131072;
    bf16_t* iKt  = wk2t + 131072;          // 16*64*64  = 65536
    bf16_t* qf   = iKt  + 65536;           // 4*16*1024*64 = 4194304
    bf16_t* kf   = qf   + 4194304;
    bf16_t* vT   = kf   + 4194304;         // 4*16*128*1024 = 8388608 (tiled)
    unsigned char* mprep = (unsigned char*)(vT + 8388608);  // 4MB uchar [B,S,S]
    // total ws use: ~39.3 MB

    conv_weights_kernel<<<dim3(1024), dim3(256), 0, stream>>>(
        wq1, wk1, wq2, wk2, iK, wq1t, wk1t, wq2t, wk2t, iKt);
    prep_mask_kernel<<<dim3(1024), dim3(256), 0, stream>>>(mask, mprep);
    conv_v_kernel<<<dim3(64, 16), dim3(256), 0, stream>>>(v, vT);
    feat_kernel<<<dim3(64, 16, 2), dim3(256), 0, stream>>>(
        q, k, wq1t, wq2t, wk1t, wk2t, iKt, sD, sD2, qf, kf);
    attn_cv_kernel<<<dim3(16, 64), dim3(256), 0, stream>>>(
        qf, kf, vT, mprep, saw, lse, out);
}

// Round 11
// 188.163 us; speedup vs baseline: 1.3328x; 1.0513x over previous
//
#include <hip/hip_runtime.h>

// KernelizedHeadAttention, B=4 S=1024 D=2048 H=16 DH=128 DHID=128 DKER=64
// out[s] = [ sum_t (m? score+eps : exp(saw)) * v[t] ] / (rowsum_s + eps + exp(lse_s))
// R11 = R10 attn (depth-2 counted-vmcnt pipeline, unchanged) + prep-stage fusion:
// prep_mask + conv_v + feat merged into ONE 4096-block kernel (task = blockIdx.x range,
// 44KB LDS union). Their streams overlap instead of running as 3 serialized
// under-utilized launches. conv_weights stays separate (feat depends on it; ~2us).

typedef __bf16 bf16_t;
typedef __attribute__((ext_vector_type(8))) __bf16 bf16x8;
typedef __attribute__((ext_vector_type(4))) float f32x4;

#define MFMA(a, b, c) __builtin_amdgcn_mfma_f32_16x16x32_bf16((a), (b), (c), 0, 0, 0)

typedef __attribute__((address_space(3))) void as3_void;
typedef __attribute__((address_space(1))) const void as1_void;
static __device__ __forceinline__ void gload16(const void* g, void* l) {
    __builtin_amdgcn_global_load_lds((as1_void*)g, (as3_void*)l, 16, 0, 0);
}

static __device__ __forceinline__ float gelu_exact(float x) {
    return 0.5f * x * (1.0f + erff(x * 0.70710678118654752f));
}

static __device__ __forceinline__ unsigned pack_bf16(float a, float b) {
    bf16_t x = (bf16_t)a, y = (bf16_t)b;
    unsigned short ux = __builtin_bit_cast(unsigned short, x);
    unsigned short uy = __builtin_bit_cast(unsigned short, y);
    return (unsigned)ux | ((unsigned)uy << 16);
}

// ---------------- weights: convert f32 -> bf16, transposed for B-fragments ----------------
__global__ __launch_bounds__(256) void conv_weights_kernel(
    const float* __restrict__ wq1, const float* __restrict__ wk1,
    const float* __restrict__ wq2, const float* __restrict__ wk2,
    const float* __restrict__ iK,
    bf16_t* __restrict__ wq1t, bf16_t* __restrict__ wk1t,
    bf16_t* __restrict__ wq2t, bf16_t* __restrict__ wk2t,
    bf16_t* __restrict__ iKt)
{
    const int idx = blockIdx.x * 256 + threadIdx.x;
    if (idx < 16 * 128 * 128) {           // [h][e][d] <- [h][d][e]
        int h = idx >> 14, e = (idx >> 7) & 127, d = idx & 127;
        wq1t[idx] = (bf16_t)wq1[(h << 14) + (d << 7) + e];
        wk1t[idx] = (bf16_t)wk1[(h << 14) + (d << 7) + e];
    }
    if (idx < 16 * 64 * 128) {            // [h][f][e] <- [h][e][f]
        int h = idx >> 13, f = (idx >> 7) & 63, e = idx & 127;
        wq2t[idx] = (bf16_t)wq2[(h << 13) + (e << 6) + f];
        wk2t[idx] = (bf16_t)wk2[(h << 13) + (e << 6) + f];
    }
    if (idx < 16 * 64 * 64) {             // [h][g][f] <- [h][f][g]
        int h = idx >> 12, g = (idx >> 6) & 63, f = idx & 63;
        iKt[idx] = (bf16_t)iK[(h << 12) + (f << 6) + g];
    }
}

// ---------------- merged prep: task 0 = mask normalize, 1 = V transpose, 2 = feat -------
__global__ __launch_bounds__(256) void prep_kernel(
    const float* __restrict__ q, const float* __restrict__ k,
    const float* __restrict__ v, const unsigned char* __restrict__ mask8,
    const bf16_t* __restrict__ wq1t, const bf16_t* __restrict__ wq2t,
    const bf16_t* __restrict__ wk1t, const bf16_t* __restrict__ wk2t,
    const bf16_t* __restrict__ iKt,
    const float* __restrict__ sD, const float* __restrict__ sD2,
    bf16_t* __restrict__ qf, bf16_t* __restrict__ kf,
    bf16_t* __restrict__ vT, unsigned char* __restrict__ mprep)
{
    __shared__ char smem[44032];
    const int bxg = blockIdx.x;
    const int tid = threadIdx.x;

    if (bxg < 1024) {
        // ---------------- task 0: mask normalize to uchar ----------------
        __shared__ int mflag;
        if (tid == 0) {     // int32 storage => bytes 4i+1 all zero over first 64 elems
            unsigned a = 0;
            for (int i = 0; i < 64; ++i) a |= mask8[4 * i + 1];
            mflag = (a == 0) ? 1 : 0;
        }
        __syncthreads();
        const size_t base = ((size_t)bxg * 256 + tid) * 16;   // 16 bytes out/thread
        if (mflag) {
            const int* mi = (const int*)mask8;
            uint4 r;
            unsigned bs[4];
#pragma unroll
            for (int j = 0; j < 4; ++j) {
                int4 vv = *reinterpret_cast<const int4*>(&mi[base + j * 4]);
                bs[j] = (vv.x ? 1u : 0u) | ((vv.y ? 1u : 0u) << 8) |
                        ((vv.z ? 1u : 0u) << 16) | ((vv.w ? 1u : 0u) << 24);
            }
            r.x = bs[0]; r.y = bs[1]; r.z = bs[2]; r.w = bs[3];
            *reinterpret_cast<uint4*>(&mprep[base]) = r;
        } else {
            uint4 vv = *reinterpret_cast<const uint4*>(&mask8[base]);
            uint4 r;
            unsigned* pv = (unsigned*)&vv;
            unsigned* pr = (unsigned*)&r;
#pragma unroll
            for (int j = 0; j < 4; ++j) {
                unsigned x = pv[j], o = 0;
#pragma unroll
                for (int kk = 0; kk < 4; ++kk)
                    o |= (((x >> (8 * kk)) & 255u) ? 1u : 0u) << (8 * kk);
                pr[j] = o;
            }
            *reinterpret_cast<uint4*>(&mprep[base]) = r;
        }
        return;
    }

    if (bxg < 2048) {
        // ---------------- task 1: V transpose -> vT [B,H,tt,128,64] bf16 ----------------
        typedef bf16_t tr_t[72];
        tr_t* tr = reinterpret_cast<tr_t*>(smem);          // [128][72]
        const int idv = bxg - 1024;
        const int bh = idv & 63, b = bh >> 4, h = bh & 15;
        const int tt = idv >> 6;
        const int t0 = tt * 64;
#pragma unroll
        for (int i = 0; i < 8; ++i) {
            int f4 = tid + 256 * i;                 // 2048 float4 = 64 t x 128 d
            int t = f4 >> 5, c4 = f4 & 31;
            const float4 vv = *reinterpret_cast<const float4*>(
                &v[((size_t)b * 1024 + t0 + t) * 2048 + h * 128 + c4 * 4]);
            tr[c4 * 4 + 0][t] = (bf16_t)vv.x;
            tr[c4 * 4 + 1][t] = (bf16_t)vv.y;
            tr[c4 * 4 + 2][t] = (bf16_t)vv.z;
            tr[c4 * 4 + 3][t] = (bf16_t)vv.w;
        }
        __syncthreads();
#pragma unroll
        for (int i = 0; i < 32; ++i) {
            int e = tid + 256 * i;                  // 8192 bf16
            int d = e >> 6, tl = e & 63;
            vT[(((size_t)bh * 16 + tt) * 128 + d) * 64 + tl] = tr[d][tl];
        }
        return;
    }

    // ---------------- task 2: feature maps ----------------
    {
        typedef bf16_t row136[136];
        typedef bf16_t row72[72];
        row136* xa = reinterpret_cast<row136*>(smem);               // [64][136]
        row136* h1 = reinterpret_cast<row136*>(smem + 17408);       // [64][136]
        row72*  k2 = reinterpret_cast<row72*>(smem + 34816);        // [64][72]

        const int idf = bxg - 2048;
        const int lane = tid & 63, w = tid >> 6;
        const int lr = lane & 15, lg = lane >> 4;
        const int row0 = (idf & 63) * 64;          // token rows over B*S=4096
        const int h = (idf >> 6) & 15;
        const int path = idf >> 10;                // 0 = q, 1 = k

        const float* X = path ? k : q;
        const bf16_t* w1t = path ? wk1t : wq1t;
        const bf16_t* w2t = path ? wk2t : wq2t;
        bf16_t* outp = path ? kf : qf;

#pragma unroll
        for (int i = 0; i < 8; ++i) {
            int f4 = tid + 256 * i;
            int r = f4 >> 5, c4 = f4 & 31;
            const float4 vv = *reinterpret_cast<const float4*>(
                &X[(size_t)(row0 + r) * 2048 + h * 128 + c4 * 4]);
            xa[r][c4 * 4 + 0] = (bf16_t)vv.x;
            xa[r][c4 * 4 + 1] = (bf16_t)vv.y;
            xa[r][c4 * 4 + 2] = (bf16_t)vv.z;
            xa[r][c4 * 4 + 3] = (bf16_t)vv.w;
        }
        __syncthreads();

        bf16x8 a1[4];
#pragma unroll
        for (int kk = 0; kk < 4; ++kk)
            a1[kk] = *reinterpret_cast<const bf16x8*>(&xa[w * 16 + lr][kk * 32 + lg * 8]);
#pragma unroll
        for (int nt = 0; nt < 8; ++nt) {
            f32x4 acc = {0.f, 0.f, 0.f, 0.f};
#pragma unroll
            for (int kk = 0; kk < 4; ++kk) {
                bf16x8 bfr = *reinterpret_cast<const bf16x8*>(
                    &w1t[(size_t)h * 16384 + (nt * 16 + lr) * 128 + kk * 32 + lg * 8]);
                acc = MFMA(a1[kk], bfr, acc);
            }
#pragma unroll
            for (int r = 0; r < 4; ++r)
                h1[w * 16 + lg * 4 + r][nt * 16 + lr] = (bf16_t)gelu_exact(acc[r]);
        }
        __syncthreads();

        bf16x8 a2[4];
#pragma unroll
        for (int kk = 0; kk < 4; ++kk)
            a2[kk] = *reinterpret_cast<const bf16x8*>(&h1[w * 16 + lr][kk * 32 + lg * 8]);

        if (path == 0) {
#pragma unroll
            for (int nt = 0; nt < 4; ++nt) {
                f32x4 acc = {0.f, 0.f, 0.f, 0.f};
#pragma unroll
                for (int kk = 0; kk < 4; ++kk) {
                    bf16x8 bfr = *reinterpret_cast<const bf16x8*>(
                        &w2t[(size_t)h * 8192 + (nt * 16 + lr) * 128 + kk * 32 + lg * 8]);
                    acc = MFMA(a2[kk], bfr, acc);
                }
#pragma unroll
                for (int r = 0; r < 4; ++r) {
                    int n = row0 + w * 16 + lg * 4 + r;
                    int bb = n >> 10, s = n & 1023;
                    outp[(((size_t)bb * 16 + h) * 1024 + s) * 64 + nt * 16 + lr] =
                        (bf16_t)fabsf(gelu_exact(acc[r]));
                }
            }
        } else {
#pragma unroll
            for (int nt = 0; nt < 4; ++nt) {
                f32x4 acc = {0.f, 0.f, 0.f, 0.f};
#pragma unroll
                for (int kk = 0; kk < 4; ++kk) {
                    bf16x8 bfr = *reinterpret_cast<const bf16x8*>(
                        &w2t[(size_t)h * 8192 + (nt * 16 + lr) * 128 + kk * 32 + lg * 8]);
                    acc = MFMA(a2[kk], bfr, acc);
                }
#pragma unroll
                for (int r = 0; r < 4; ++r) {
                    int f = nt * 16 + lr;
                    k2[w * 16 + lg * 4 + r][f] =
                        (bf16_t)(fabsf(sD[h * 64 + f]) * gelu_exact(acc[r]));
                }
            }
            __syncthreads();
            bf16x8 a3[2];
#pragma unroll
            for (int kk = 0; kk < 2; ++kk)
                a3[kk] = *reinterpret_cast<const bf16x8*>(&k2[w * 16 + lr][kk * 32 + lg * 8]);
#pragma unroll
            for (int nt = 0; nt < 4; ++nt) {
                f32x4 acc = {0.f, 0.f, 0.f, 0.f};
#pragma unroll
                for (int kk = 0; kk < 2; ++kk) {
                    bf16x8 bfr = *reinterpret_cast<const bf16x8*>(
                        &iKt[(size_t)h * 4096 + (nt * 16 + lr) * 64 + kk * 32 + lg * 8]);
                    acc = MFMA(a3[kk], bfr, acc);
                }
#pragma unroll
                for (int r = 0; r < 4; ++r) {
                    int row = w * 16 + lg * 4 + r;
                    int g = nt * 16 + lr;
                    float base = (float)k2[row][g];
                    float kv = fabsf(base + acc[r] * sD2[h * 64 + g]);
                    int n = row0 + row;
                    int bb = n >> 10, s = n & 1023;
                    outp[(((size_t)bb * 16 + h) * 1024 + s) * 64 + g] = (bf16_t)kv;
                }
            }
        }
    }
}

// ---------------- fused attention: depth-2 staging, triple-buffer, counted vmcnt --------
__global__ __launch_bounds__(256, 2) void attn_cv_kernel(
    const bf16_t* __restrict__ qf, const bf16_t* __restrict__ kf,
    const bf16_t* __restrict__ vT,
    const unsigned char* __restrict__ mprep,
    const float* __restrict__ saw, const float* __restrict__ lse,
    float* __restrict__ out)
{
    __shared__ bf16_t vbuf[3][128 * 64];      // XOR-swizzled V tiles (16KB each)
    __shared__ bf16_t kbuf[3][64 * 64];       // XOR-swizzled K tiles (8KB each)

    const int tid = threadIdx.x;
    const int lane = tid & 63, w = tid >> 6;
    const int lr = lane & 15, lg = lane >> 4;

    // XCD swizzle: all 16 s-blocks of a bh share one XCD's L2
    const int di = blockIdx.y * 16 + blockIdx.x;   // 0..1023
    const int xcd = di & 7, rr = di >> 3;
    const int bh = xcd + 8 * (rr >> 4);
    const int s0 = (rr & 15) * 64;
    const int b = bh >> 4, h = bh & 15;

    const int srow = s0 + w * 16 + lr;             // this lane's single s-row
    const size_t saw_row = ((size_t)bh << 20) + (size_t)srow * 1024;
    const size_t m_row   = ((size_t)b << 20) + (size_t)srow * 1024;

    // staging mapping (inverse-swizzled global source, linear LDS dest)
    const int vrow = tid >> 3;                     // 0..31
    const int vcol8 = (tid & 7) ^ (vrow & 7);
    const bf16_t* vt_bh = vT + (size_t)bh * 131072;
    const bf16_t* kf_bh = kf + (size_t)bh * 65536;

    // Q as B-fragments (n = s, k = f)
    bf16x8 aq0, aq1;
    {
        const size_t qb = ((size_t)bh * 1024 + srow) * 64;
        aq0 = *reinterpret_cast<const bf16x8*>(&qf[qb + lg * 8]);
        aq1 = *reinterpret_cast<const bf16x8*>(&qf[qb + 32 + lg * 8]);
    }

    const f32x4 fzero = {0.f, 0.f, 0.f, 0.f};
    f32x4 oacc[8];
#pragma unroll
    for (int i = 0; i < 8; ++i) oacc[i] = fzero;
    float rs = 0.f;

#define STAGE_VT(BUF, TILE)                                                      \
    {                                                                            \
        const bf16_t* vg = vt_bh + (size_t)(TILE) * 8192 + vcol8 * 8;            \
        char* lb = (char*)&vbuf[BUF][0] + w * 1024;                              \
        _Pragma("unroll")                                                        \
        for (int j = 0; j < 4; ++j)                                              \
            gload16(vg + (size_t)(32 * j + vrow) * 64, lb + j * 4096);           \
    }

#define STAGE_KF(BUF, TILE)                                                      \
    {                                                                            \
        const bf16_t* kg = kf_bh + (size_t)(TILE) * 4096 + vcol8 * 8;            \
        char* lb = (char*)&kbuf[BUF][0] + w * 1024;                              \
        _Pragma("unroll")                                                        \
        for (int j = 0; j < 2; ++j)                                              \
            gload16(kg + (size_t)(32 * j + vrow) * 64, lb + j * 4096);           \
    }

#define LOAD_SAW(TILE, SS, MM)                                                   \
    {                                                                            \
        _Pragma("unroll")                                                        \
        for (int nt = 0; nt < 4; ++nt) {                                         \
            SS[nt] = *reinterpret_cast<const f32x4*>(                            \
                &saw[saw_row + (size_t)(TILE) * 64 + nt * 16 + lg * 4]);         \
            MM[nt] = *reinterpret_cast<const unsigned*>(                         \
                &mprep[m_row + (size_t)(TILE) * 64 + nt * 16 + lg * 4]);         \
        }                                                                        \
    }

// QK^T from swizzled kbuf + register merge -> pk[8] (bf16 pairs), rowsum rs
#define QKT_MERGE(CUR, SS, MM)                                                   \
    {                                                                            \
        _Pragma("unroll")                                                        \
        for (int nt = 0; nt < 4; ++nt) {                                         \
            const int row = nt * 16 + lr;                                        \
            const char* kb = (const char*)&kbuf[CUR][0] + row * 128;             \
            const int sw = (row & 7) * 16;                                       \
            bf16x8 k0 = *reinterpret_cast<const bf16x8*>(kb + ((lg * 16) ^ sw)); \
            bf16x8 k1 = *reinterpret_cast<const bf16x8*>(kb + ((64 + lg * 16) ^ sw)); \
            f32x4 acc = fzero;                                                   \
            acc = MFMA(k0, aq0, acc);                                            \
            acc = MFMA(k1, aq1, acc);                                            \
            const unsigned mm = MM[nt];                                          \
            float v0, v1, v2, v3;                                                \
            v0 = (mm & 255u)         ? (acc[0] + 1e-6f) : __expf(SS[nt][0]);     \
            rs += (mm & 255u)         ? acc[0] : 0.f;                            \
            v1 = ((mm >> 8) & 255u)  ? (acc[1] + 1e-6f) : __expf(SS[nt][1]);     \
            rs += ((mm >> 8) & 255u)  ? acc[1] : 0.f;                            \
            v2 = ((mm >> 16) & 255u) ? (acc[2] + 1e-6f) : __expf(SS[nt][2]);     \
            rs += ((mm >> 16) & 255u) ? acc[2] : 0.f;                            \
            v3 = (mm >> 24)          ? (acc[3] + 1e-6f) : __expf(SS[nt][3]);     \
            rs += (mm >> 24)          ? acc[3] : 0.f;                            \
            pk[nt * 2]     = pack_bf16(v0, v1);                                  \
            pk[nt * 2 + 1] = pack_bf16(v2, v3);                                  \
        }                                                                        \
    }

// redistribute P across the 4 lanes sharing lr -> PV B-fragments.
// ALL shuffles at full EXEC; selection is a pure cndmask on shuffled values.
#define REDIST()                                                                 \
    {                                                                            \
        const int srcA = lr + ((lg & 1) << 5);                                   \
        const int srcB = srcA + 16;                                              \
        const bool sel = (lg < 2);                                               \
        const unsigned a0 = __shfl(pk[0], srcA, 64);                             \
        const unsigned a1 = __shfl(pk[1], srcA, 64);                             \
        const unsigned a2 = __shfl(pk[2], srcA, 64);                             \
        const unsigned a3 = __shfl(pk[3], srcA, 64);                             \
        const unsigned b0 = __shfl(pk[0], srcB, 64);                             \
        const unsigned b1 = __shfl(pk[1], srcB, 64);                             \
        const unsigned b2 = __shfl(pk[2], srcB, 64);                             \
        const unsigned b3 = __shfl(pk[3], srcB, 64);                             \
        f0w.x = sel ? a0 : a2;  f0w.y = sel ? a1 : a3;                           \
        f0w.z = sel ? b0 : b2;  f0w.w = sel ? b1 : b3;                           \
        const unsigned c4 = __shfl(pk[4], srcA, 64);                             \
        const unsigned c5 = __shfl(pk[5], srcA, 64);                             \
        const unsigned c6 = __shfl(pk[6], srcA, 64);                             \
        const unsigned c7 = __shfl(pk[7], srcA, 64);                             \
        const unsigned d4 = __shfl(pk[4], srcB, 64);                             \
        const unsigned d5 = __shfl(pk[5], srcB, 64);                             \
        const unsigned d6 = __shfl(pk[6], srcB, 64);                             \
        const unsigned d7 = __shfl(pk[7], srcB, 64);                             \
        f1w.x = sel ? c4 : c6;  f1w.y = sel ? c5 : c7;                           \
        f1w.z = sel ? d4 : d6;  f1w.w = sel ? d5 : d7;                           \
    }

#define PV(CUR)                                                                  \
    {                                                                            \
        bf16x8 pf0 = __builtin_bit_cast(bf16x8, f0w);                            \
        bf16x8 pf1 = __builtin_bit_cast(bf16x8, f1w);                            \
        __builtin_amdgcn_s_setprio(1);                                           \
        _Pragma("unroll")                                                        \
        for (int dt = 0; dt < 8; ++dt) {                                         \
            const int row = dt * 16 + lr;                                        \
            const char* vb = (const char*)&vbuf[CUR][0] + row * 128;             \
            const int sw = (row & 7) * 16;                                       \
            bf16x8 v0 = *reinterpret_cast<const bf16x8*>(vb + ((lg * 16) ^ sw)); \
            bf16x8 v1 = *reinterpret_cast<const bf16x8*>(vb + ((64 + lg * 16) ^ sw)); \
            oacc[dt] = MFMA(v0, pf0, oacc[dt]);                                  \
            oacc[dt] = MFMA(v1, pf1, oacc[dt]);                                  \
        }                                                                        \
        __builtin_amdgcn_s_setprio(0);                                           \
    }

// one phase: stage(i+2) -> counted wait for stage(i) -> barrier -> compute(i) -> barrier
#define FULL_PHASE(CIDX, SIDX, TSTAGE, SS, MM, TSAW)                             \
    {                                                                            \
        STAGE_VT(SIDX, TSTAGE);                                                  \
        STAGE_KF(SIDX, TSTAGE);                                                  \
        __builtin_amdgcn_sched_barrier(0);                                       \
        asm volatile("s_waitcnt vmcnt(28)" ::: "memory");                        \
        __builtin_amdgcn_s_barrier();                                            \
        __builtin_amdgcn_sched_barrier(0);                                       \
        QKT_MERGE(CIDX, SS, MM);                                                 \
        REDIST();                                                                \
        LOAD_SAW(TSAW, SS, MM);                                                  \
        __builtin_amdgcn_sched_barrier(0);                                       \
        PV(CIDX);                                                                \
        __builtin_amdgcn_sched_barrier(0);                                       \
        __builtin_amdgcn_s_barrier();                                            \
    }

    f32x4 sawA[4], sawB[4];
    unsigned muA[4], muB[4];
    unsigned pk[8];
    uint4 f0w, f1w;

    // ---- prologue: stage tiles 0,1 (bufs 0,1); saw tiles 0,1 (depth 2)
    STAGE_VT(0, 0);
    STAGE_KF(0, 0);
    LOAD_SAW(0, sawA, muA);
    STAGE_VT(1, 1);
    STAGE_KF(1, 1);
    LOAD_SAW(1, sawB, muB);

    int c0 = 0, c1 = 1, c2 = 2;
    // main loop: phases 0..13 (each iteration = 2 phases; phase i stages tile i+2)
    for (int i = 0; i < 14; i += 2) {
        FULL_PHASE(c0, c2, i + 2, sawA, muA, i + 2);        // phase i
        FULL_PHASE(c1, c0, i + 3, sawB, muB, i + 3);        // phase i+1
        const int t_ = c0; c0 = c2; c2 = c1; c1 = t_;       // rotate
    }
    // after 7 rotations: c0 = buf of tile 14, c1 = buf of tile 15

    // peeled phase 14: no staging; stage(14) has 22 newer ops (saw14:8+stage15:6+saw15:8)
    {
        asm volatile("s_waitcnt vmcnt(22)" ::: "memory");
        __builtin_amdgcn_s_barrier();
        __builtin_amdgcn_sched_barrier(0);
        QKT_MERGE(c0, sawA, muA);
        REDIST();
        __builtin_amdgcn_sched_barrier(0);
        PV(c0);
        __builtin_amdgcn_sched_barrier(0);
        __builtin_amdgcn_s_barrier();
    }
    // peeled phase 15: stage(15) has 8 newer ops (saw15)
    {
        asm volatile("s_waitcnt vmcnt(8)" ::: "memory");
        __builtin_amdgcn_s_barrier();
        __builtin_amdgcn_sched_barrier(0);
        QKT_MERGE(c1, sawB, muB);
        REDIST();
        __builtin_amdgcn_sched_barrier(0);
        PV(c1);
    }

    // rowsum: sum the 4 lg-partials for this s-row
    rs += __shfl_xor(rs, 16);
    rs += __shfl_xor(rs, 32);
    const float invden =
        1.0f / (rs + 1e-6f + __expf(lse[(size_t)bh * 1024 + srow]));

    const size_t ob = ((size_t)b * 1024 + srow) * 2048 + h * 128 + lg * 4;
#pragma unroll
    for (int dt = 0; dt < 8; ++dt) {
        f32x4 o;
        o[0] = oacc[dt][0] * invden;
        o[1] = oacc[dt][1] * invden;
        o[2] = oacc[dt][2] * invden;
        o[3] = oacc[dt][3] * invden;
        *reinterpret_cast<f32x4*>(&out[ob + dt * 16]) = o;
    }
#undef STAGE_VT
#undef STAGE_KF
#undef LOAD_SAW
#undef QKT_MERGE
#undef REDIST
#undef PV
#undef FULL_PHASE
}

extern "C" void kernel_launch(void* const* d_in, const int* in_sizes, int n_in,
                              void* d_out, int out_size, void* d_ws, size_t ws_size,
                              hipStream_t stream)
{
    const float* q   = (const float*)d_in[0];
    const float* k   = (const float*)d_in[1];
    const float* v   = (const float*)d_in[2];
    const unsigned char* mask = (const unsigned char*)d_in[3];
    const float* lse = (const float*)d_in[4];
    const float* saw = (const float*)d_in[5];
    const float* wq1 = (const float*)d_in[6];
    const float* wk1 = (const float*)d_in[7];
    const float* wq2 = (const float*)d_in[8];
    const float* wk2 = (const float*)d_in[9];
    const float* iK  = (const float*)d_in[10];
    const float* sD  = (const float*)d_in[11];
    const float* sD2 = (const float*)d_in[12];
    float* out = (float*)d_out;

    bf16_t* wsb  = (bf16_t*)d_ws;
    bf16_t* wq1t = wsb;                    // 16*128*128 = 262144
    bf16_t* wk1t = wq1t + 262144;
    bf16_t* wq2t = wk1t + 262144;          // 16*64*128 = 131072
    bf16_t* wk2t = wq2t + 131072;
    bf16_t* iKt  = wk2t + 131072;          // 16*64*64  = 65536
    bf16_t* qf   = iKt  + 65536;           // 4*16*1024*64 = 4194304
    bf16_t* kf   = qf   + 4194304;
    bf16_t* vT   = kf   + 4194304;         // 4*16*128*1024 = 8388608 (tiled)
    unsigned char* mprep = (unsigned char*)(vT + 8388608);  // 4MB uchar [B,S,S]
    // total ws use: ~39.3 MB

    conv_weights_kernel<<<dim3(1024), dim3(256), 0, stream>>>(
        wq1, wk1, wq2, wk2, iK, wq1t, wk1t, wq2t, wk2t, iKt);
    prep_kernel<<<dim3(4096), dim3(256), 0, stream>>>(
        q, k, v, mask, wq1t, wq2t, wk1t, wk2t, iKt, sD, sD2, qf, kf, vT, mprep);
    attn_cv_kernel<<<dim3(16, 64), dim3(256), 0, stream>>>(
        qf, kf, vT, mprep, saw, lse, out);
}